// Round 20
// baseline (255.765 us; speedup 1.0000x reference)
//
#include <hip/hip_runtime.h>
#include <hip/hip_bf16.h>
#include <math.h>

#define SEQ   2048
#define BATCH 2
#define NROWS 4096      /* BATCH*SEQ */
#define DIMM  1024
#define QKV3  3072
#define FFD   4096
#define NHEAD 16
#define DHEAD 64

typedef __bf16 bf16;
typedef __bf16 bf16x4 __attribute__((ext_vector_type(4)));
typedef __bf16 bf16x8 __attribute__((ext_vector_type(8)));
typedef float  f32x4  __attribute__((ext_vector_type(4)));

static __device__ __forceinline__ f32x4 mfma16(bf16x8 a, bf16x8 b, f32x4 c) {
    return __builtin_amdgcn_mfma_f32_16x16x32_bf16(a, b, c, 0, 0, 0);
}

#define GLDS16(gp, lp) __builtin_amdgcn_global_load_lds( \
    (__attribute__((address_space(1))) void*)(gp),       \
    (__attribute__((address_space(3))) void*)(lp), 16, 0, 0)

#define MEMFENCE asm volatile("" ::: "memory")

// ---------------------------------------------------------------------------
// Merged weight transpose+cast: all 4 matrices in ONE launch.
//   tiles: wqkv 3072 | wout 1024 | wff1 4096 | wff2 4096  (total 12288)
// ---------------------------------------------------------------------------
__global__ __launch_bounds__(256) void wcast_kernel(
    const float* __restrict__ wqkv, bf16* __restrict__ wqkvT,
    const float* __restrict__ wout, bf16* __restrict__ woutT,
    const float* __restrict__ wff1, bf16* __restrict__ wff1T,
    const float* __restrict__ wff2, bf16* __restrict__ wff2T)
{
    int t = blockIdx.x;
    const float* src; bf16* dst; int K, N, nx;
    if (t < 3072)      { src = wqkv; dst = wqkvT; K = DIMM; N = QKV3; nx = 96;  }
    else if (t < 4096) { src = wout; dst = woutT; K = DIMM; N = DIMM; nx = 32; t -= 3072; }
    else if (t < 8192) { src = wff1; dst = wff1T; K = DIMM; N = FFD;  nx = 128; t -= 4096; }
    else               { src = wff2; dst = wff2T; K = FFD;  N = DIMM; nx = 32; t -= 8192; }
    const int k0 = (t / nx) * 32;
    const int n0 = (t - (t / nx) * nx) * 32;

    __shared__ float tile[32][33];
    const int r = threadIdx.x >> 5;   // 0..7
    const int c = threadIdx.x & 31;
    #pragma unroll
    for (int i = 0; i < 4; ++i)
        tile[r + 8 * i][c] = src[(size_t)(k0 + r + 8 * i) * N + n0 + c];
    __syncthreads();
    #pragma unroll
    for (int i = 0; i < 4; ++i)
        dst[(size_t)(n0 + r + 8 * i) * K + k0 + c] = (bf16)tile[c][r + 8 * i];
}

// ---------------------------------------------------------------------------
// LayerNorm fp32 [NROWS][1024] -> bf16, one block per row
// ---------------------------------------------------------------------------
__global__ __launch_bounds__(256) void ln_cast_kernel(
    const float* __restrict__ x, const float* __restrict__ g,
    const float* __restrict__ b, bf16* __restrict__ out)
{
    const int row = blockIdx.x;
    const int t = threadIdx.x;
    const float4 v = ((const float4*)(x + (size_t)row * DIMM))[t];
    float s  = v.x + v.y + v.z + v.w;
    float sq = v.x * v.x + v.y * v.y + v.z * v.z + v.w * v.w;
    #pragma unroll
    for (int m = 1; m < 64; m <<= 1) {
        s  += __shfl_xor(s, m, 64);
        sq += __shfl_xor(sq, m, 64);
    }
    __shared__ float ss[4], ssq[4];
    const int wave = t >> 6;
    if ((t & 63) == 0) { ss[wave] = s; ssq[wave] = sq; }
    __syncthreads();
    s  = ss[0] + ss[1] + ss[2] + ss[3];
    sq = ssq[0] + ssq[1] + ssq[2] + ssq[3];
    const float mean = s * (1.0f / DIMM);
    const float var  = sq * (1.0f / DIMM) - mean * mean;
    const float rs   = rsqrtf(var + 1e-5f);
    const float4 gv = ((const float4*)g)[t];
    const float4 bv = ((const float4*)b)[t];
    bf16* o = out + (size_t)row * DIMM + t * 4;
    o[0] = (bf16)((v.x - mean) * rs * gv.x + bv.x);
    o[1] = (bf16)((v.y - mean) * rs * gv.y + bv.y);
    o[2] = (bf16)((v.z - mean) * rs * gv.z + bv.z);
    o[3] = (bf16)((v.w - mean) * rs * gv.w + bv.w);
}

// ---------------------------------------------------------------------------
// 256x256 8-wave GEMM — 4-phase fine-interleaved schedule (r13/r14 proven).
// Used for FF1 only (grid 256 = exactly 1 block/CU).
// EPI: 2 = +bias, GELU, bf16 out
// ---------------------------------------------------------------------------
template<int EPI>
__global__ __launch_bounds__(512, 2)
void gemm256_kernel(const bf16* __restrict__ A, const bf16* __restrict__ BT,
                    const float* __restrict__ bias, bf16* __restrict__ C,
                    int M, int N, int K, int ld)
{
    __shared__ bf16 As_[2][2][8192];   // [dbuf][half][128 rows x 64 k]
    __shared__ bf16 Bs_[2][2][8192];
    const int nb = N >> 8;
    const int chunk = (int)gridDim.x >> 3;
    const int idx = ((int)blockIdx.x & 7) * chunk + ((int)blockIdx.x >> 3);
    const int bm = idx / nb, bn = idx - bm * nb;
    const int tm = bm << 8, tn = bn << 8;
    const int tid = threadIdx.x;
    const int lane = tid & 63, w = tid >> 6;   // 8 waves
    const int wr = w >> 2, wc = w & 3;
    const int lq = lane & 15, hk = lane >> 4;

    const int sr  = lane >> 3;
    const int sgo = (((lane & 7) ^ sr) << 3);
    const bf16* gA0 = A  + (size_t)(tm +       w * 8 + sr) * ld + sgo;
    const bf16* gA1 = A  + (size_t)(tm + 128 + w * 8 + sr) * ld + sgo;
    const bf16* gB0 = BT + (size_t)(tn +       w * 8 + sr) * ld + sgo;
    const bf16* gB1 = BT + (size_t)(tn + 128 + w * 8 + sr) * ld + sgo;
    const size_t l64 = (size_t)64 * ld;

#define STG_A0(D, T) do { const size_t ko_ = (size_t)(T) * 64;              \
        GLDS16(gA0 + ko_,       &As_[D][0][w * 512]);                       \
        GLDS16(gA0 + ko_ + l64, &As_[D][0][4096 + w * 512]); } while (0)
#define STG_A1(D, T) do { const size_t ko_ = (size_t)(T) * 64;              \
        GLDS16(gA1 + ko_,       &As_[D][1][w * 512]);                       \
        GLDS16(gA1 + ko_ + l64, &As_[D][1][4096 + w * 512]); } while (0)
#define STG_B0(D, T) do { const size_t ko_ = (size_t)(T) * 64;              \
        GLDS16(gB0 + ko_,       &Bs_[D][0][w * 512]);                       \
        GLDS16(gB0 + ko_ + l64, &Bs_[D][0][4096 + w * 512]); } while (0)
#define STG_B1(D, T) do { const size_t ko_ = (size_t)(T) * 64;              \
        GLDS16(gB1 + ko_,       &Bs_[D][1][w * 512]);                       \
        GLDS16(gB1 + ko_ + l64, &Bs_[D][1][4096 + w * 512]); } while (0)

    f32x4 acc[8][4] = {};
    const int NT = K >> 6;

    STG_A0(0, 0); STG_B1(0, 0); STG_B0(0, 0); STG_A1(0, 0);
    STG_B0(1, 1); STG_A1(1, 1);

    for (int t = 0; t < NT; ++t) {
        const int d = t & 1, e = d ^ 1;
        if (t == NT - 1) asm volatile("s_waitcnt vmcnt(0)" ::: "memory");
        else             asm volatile("s_waitcnt vmcnt(4)" ::: "memory");
        __builtin_amdgcn_s_barrier();
        MEMFENCE;

        const char* Ah0 = (const char*)&As_[d][0][0];
        const char* Ah1 = (const char*)&As_[d][1][0];
        const char* Bh0 = (const char*)&Bs_[d][0][0];
        const char* Bh1 = (const char*)&Bs_[d][1][0];
        bf16x8 af[4][2], bfv[2][2];

#define DO_MFMA(MH, NH) do {                                                 \
        __builtin_amdgcn_s_setprio(1);                                       \
        _Pragma("unroll")                                                    \
        for (int mi = 0; mi < 4; ++mi)                                       \
            _Pragma("unroll")                                                \
            for (int nj = 0; nj < 2; ++nj)                                   \
                _Pragma("unroll")                                            \
                for (int kk = 0; kk < 2; ++kk)                               \
                    acc[(MH)*4+mi][(NH)*2+nj] =                              \
                        mfma16(bfv[nj][kk], af[mi][kk], acc[(MH)*4+mi][(NH)*2+nj]); \
        __builtin_amdgcn_s_setprio(0); } while (0)

        {   // ph1 (0,0)
            #pragma unroll
            for (int mi = 0; mi < 4; ++mi) {
                const int lr = wr * 64 + mi * 16 + lq;
                af[mi][0] = *(const bf16x8*)(Ah0 + lr * 128 + ((hk ^ (lr & 7)) << 4));
                af[mi][1] = *(const bf16x8*)(Ah0 + lr * 128 + (((4 + hk) ^ (lr & 7)) << 4));
            }
            #pragma unroll
            for (int nj = 0; nj < 2; ++nj) {
                const int lc = wc * 32 + nj * 16 + lq;
                bfv[nj][0] = *(const bf16x8*)(Bh0 + lc * 128 + ((hk ^ (lc & 7)) << 4));
                bfv[nj][1] = *(const bf16x8*)(Bh0 + lc * 128 + (((4 + hk) ^ (lc & 7)) << 4));
            }
            if (t + 1 < NT) STG_A0(e, t + 1);
            DO_MFMA(0, 0);
        }
        MEMFENCE; __builtin_amdgcn_s_barrier(); MEMFENCE;
        {   // ph2 (1,0)
            #pragma unroll
            for (int mi = 0; mi < 4; ++mi) {
                const int lr = wr * 64 + mi * 16 + lq;
                af[mi][0] = *(const bf16x8*)(Ah1 + lr * 128 + ((hk ^ (lr & 7)) << 4));
                af[mi][1] = *(const bf16x8*)(Ah1 + lr * 128 + (((4 + hk) ^ (lr & 7)) << 4));
            }
            if (t + 1 < NT) STG_B1(e, t + 1);
            DO_MFMA(1, 0);
        }
        MEMFENCE; __builtin_amdgcn_s_barrier(); MEMFENCE;
        {   // ph3 (1,1)
            #pragma unroll
            for (int nj = 0; nj < 2; ++nj) {
                const int lc = wc * 32 + nj * 16 + lq;
                bfv[nj][0] = *(const bf16x8*)(Bh1 + lc * 128 + ((hk ^ (lc & 7)) << 4));
                bfv[nj][1] = *(const bf16x8*)(Bh1 + lc * 128 + (((4 + hk) ^ (lc & 7)) << 4));
            }
            if (t + 2 < NT) STG_B0(d, t + 2);
            DO_MFMA(1, 1);
        }
        MEMFENCE; __builtin_amdgcn_s_barrier(); MEMFENCE;
        {   // ph4 (0,1)
            #pragma unroll
            for (int mi = 0; mi < 4; ++mi) {
                const int lr = wr * 64 + mi * 16 + lq;
                af[mi][0] = *(const bf16x8*)(Ah0 + lr * 128 + ((hk ^ (lr & 7)) << 4));
                af[mi][1] = *(const bf16x8*)(Ah0 + lr * 128 + (((4 + hk) ^ (lr & 7)) << 4));
            }
            if (t + 2 < NT) STG_A1(d, t + 2);
            DO_MFMA(0, 1);
        }
        MEMFENCE; __builtin_amdgcn_s_barrier(); MEMFENCE;
#undef DO_MFMA
    }
#undef STG_A0
#undef STG_A1
#undef STG_B0
#undef STG_B1

    #pragma unroll
    for (int i = 0; i < 8; ++i) {
        const int mh = i >> 2, mi = i & 3;
        const int row = tm + mh * 128 + wr * 64 + mi * 16 + lq;
        #pragma unroll
        for (int j = 0; j < 4; ++j) {
            const int nh = j >> 1, nj = j & 1;
            const int col = tn + nh * 128 + wc * 32 + nj * 16 + (hk << 2);
            if (EPI == 0) {
                bf16x4 pk = { (bf16)acc[i][j][0], (bf16)acc[i][j][1],
                              (bf16)acc[i][j][2], (bf16)acc[i][j][3] };
                *(bf16x4*)(C + (size_t)row * N + col) = pk;
            } else {
                const float4 bv4 = *(const float4*)(bias + col);
                float v0 = acc[i][j][0] + bv4.x, v1 = acc[i][j][1] + bv4.y;
                float v2 = acc[i][j][2] + bv4.z, v3 = acc[i][j][3] + bv4.w;
                bf16x4 pk = {
                    (bf16)(0.5f * v0 * (1.0f + erff(v0 * 0.70710678118654752f))),
                    (bf16)(0.5f * v1 * (1.0f + erff(v1 * 0.70710678118654752f))),
                    (bf16)(0.5f * v2 * (1.0f + erff(v2 * 0.70710678118654752f))),
                    (bf16)(0.5f * v3 * (1.0f + erff(v3 * 0.70710678118654752f))) };
                *(bf16x4*)(C + (size_t)row * N + col) = pk;
            }
        }
    }
}

// ---------------------------------------------------------------------------
// 128x128 3-stage counted-vmcnt GEMM + swapped-operand vectorized epilogue.
// Used for QKV (768 blk, 3/CU), out-proj, FF2 split-K.
// EPI: 0 = bf16 out; 1 = +bias +residual, fp32 out; 3 = split-K partial
// ---------------------------------------------------------------------------
template<int EPI>
__global__ __launch_bounds__(256, 3)
void gemm_bt_kernel(const bf16* __restrict__ A, const bf16* __restrict__ BT,
                    const float* __restrict__ bias, const float* __restrict__ res,
                    void* __restrict__ Cout, int M, int N, int K, int ld)
{
    __shared__ bf16 As[3][4096];   // [buf][128 m][32 k]
    __shared__ bf16 Bs[3][4096];
    const int nb = N >> 7;
    const int chunk = (int)gridDim.x >> 3;
    int idx = (blockIdx.x & 7) * chunk + (blockIdx.x >> 3);
    int ks = 0;
    if (EPI == 3) {
        const int tiles = (M >> 7) * nb;
        ks = idx / tiles;
        idx -= ks * tiles;
    }
    const int bm = idx / nb, bn = idx - bm * nb;
    const int tm = bm << 7, tn = bn << 7;
    const int tid = threadIdx.x;
    const int lane = tid & 63, wave = tid >> 6;
    const int wm = (wave >> 1) << 6, wn = (wave & 1) << 6;
    const int kofs = ks * K;

    const bf16* ga = A  + (size_t)(tm + wave * 32 + (lane >> 2)) * ld + kofs + ((lane & 3) << 3);
    const bf16* gb = BT + (size_t)(tn + wave * 32 + (lane >> 2)) * ld + kofs + ((lane & 3) << 3);
    const size_t k16 = (size_t)16 * ld;

    f32x4 acc[4][4] = {};
    const int ro = (lane & 15) * 32 + ((lane >> 4) << 3);

#define GSTAGE(BUF, KO) do {                          \
        bf16* la_ = &As[BUF][wave * 1024];            \
        bf16* lb_ = &Bs[BUF][wave * 1024];            \
        GLDS16(ga + (KO),       la_);                 \
        GLDS16(ga + (KO) + k16, la_ + 512);           \
        GLDS16(gb + (KO),       lb_);                 \
        GLDS16(gb + (KO) + k16, lb_ + 512);           \
    } while (0)

    GSTAGE(0, 0);
    GSTAGE(1, 32);
    GSTAGE(2, 64);
    int cur = 0;
    for (int k0 = 0; k0 < K; k0 += 32) {
        if (k0 + 96 <= K)      asm volatile("s_waitcnt vmcnt(8)" ::: "memory");
        else if (k0 + 64 <= K) asm volatile("s_waitcnt vmcnt(4)" ::: "memory");
        else                   asm volatile("s_waitcnt vmcnt(0)" ::: "memory");
        __builtin_amdgcn_s_barrier();

        bf16x8 af[4], bfr[4];
        #pragma unroll
        for (int i = 0; i < 4; ++i) {
            af[i]  = *(const bf16x8*)(&As[cur][0] + (wm + i * 16) * 32 + ro);
            bfr[i] = *(const bf16x8*)(&Bs[cur][0] + (wn + i * 16) * 32 + ro);
        }
        #pragma unroll
        for (int i = 0; i < 4; ++i)
            #pragma unroll
            for (int j = 0; j < 4; ++j)
                acc[i][j] = mfma16(bfr[j], af[i], acc[i][j]);   // swapped

        MEMFENCE;
        __builtin_amdgcn_s_barrier();
        MEMFENCE;
        if (k0 + 96 < K) GSTAGE(cur, k0 + 96);
        cur = (cur == 2) ? 0 : cur + 1;
    }
#undef GSTAGE

    // swapped layout: acc[i][j][r] = C[tm+wm+i*16+lq][tn+wn+j*16+hk*4+r]
    const int lq = lane & 15, hk = lane >> 4;
    const int r0 = tm + wm + lq;
    const int c0 = tn + wn + (hk << 2);
    if (EPI == 0) {
        bf16* C = (bf16*)Cout;
        #pragma unroll
        for (int j = 0; j < 4; ++j)
            #pragma unroll
            for (int i = 0; i < 4; ++i) {
                bf16x4 pk = { (bf16)acc[i][j][0], (bf16)acc[i][j][1],
                              (bf16)acc[i][j][2], (bf16)acc[i][j][3] };
                *(bf16x4*)(C + (size_t)(r0 + i * 16) * N + c0 + j * 16) = pk;
            }
    } else if (EPI == 1) {
        float* C = (float*)Cout;
        #pragma unroll
        for (int j = 0; j < 4; ++j) {
            const float4 bv4 = *(const float4*)(bias + c0 + j * 16);
            #pragma unroll
            for (int i = 0; i < 4; ++i) {
                const size_t off = (size_t)(r0 + i * 16) * N + c0 + j * 16;
                const float4 rv = *(const float4*)(res + off);
                float4 o;
                o.x = acc[i][j][0] + bv4.x + rv.x;
                o.y = acc[i][j][1] + bv4.y + rv.y;
                o.z = acc[i][j][2] + bv4.z + rv.z;
                o.w = acc[i][j][3] + bv4.w + rv.w;
                *(float4*)(C + off) = o;
            }
        }
    } else {
        float* C = (float*)(ks == 0 ? Cout : (void*)res);
        #pragma unroll
        for (int j = 0; j < 4; ++j)
            #pragma unroll
            for (int i = 0; i < 4; ++i) {
                float4 o = { acc[i][j][0], acc[i][j][1], acc[i][j][2], acc[i][j][3] };
                *(float4*)(C + (size_t)(r0 + i * 16) * N + c0 + j * 16) = o;
            }
    }
}

// ---------------------------------------------------------------------------
// FF2 split-K reduce: out = p0 + p1 + bias + res  (all fp32, [NROWS][DIMM])
// ---------------------------------------------------------------------------
__global__ __launch_bounds__(256) void ff2_reduce_kernel(
    const float* __restrict__ p0, const float* __restrict__ p1,
    const float* __restrict__ bias, const float* __restrict__ res,
    float* __restrict__ out)
{
    const int i = blockIdx.x * 256 + threadIdx.x;    // float4 index
    const float4 a = ((const float4*)p0)[i];
    const float4 b = ((const float4*)p1)[i];
    const float4 r = ((const float4*)res)[i];
    const float4 g = ((const float4*)bias)[i & 255];
    float4 o;
    o.x = a.x + b.x + r.x + g.x;
    o.y = a.y + b.y + r.y + g.y;
    o.z = a.z + b.z + r.z + g.z;
    o.w = a.w + b.w + r.w + g.w;
    ((float4*)out)[i] = o;
}

// ---------------------------------------------------------------------------
// V transpose per head, PERMUTED columns (r18 proven): within each 32-column
// block, position n' holds V column n with
//   n' = (n&3) | ((n>>4)&1)<<2 | ((n>>2)&3)<<3
// ---------------------------------------------------------------------------
__global__ __launch_bounds__(256) void vtrans_kernel(
    const bf16* __restrict__ qkv, bf16* __restrict__ vT)
{
    __shared__ bf16 t[64 * 64];
    const int n0 = blockIdx.x * 64;
    const int bh = blockIdx.y;
    const int b = bh >> 4, h = bh & 15;
    const bf16* src = qkv + (size_t)(b * SEQ + n0) * QKV3 + 2 * DIMM + h * DHEAD;

    #pragma unroll
    for (int it = 0; it < 2; ++it) {
        const int c = it * 256 + threadIdx.x;
        const int n = c >> 3, d8 = (c & 7) * 8;
        const bf16x8 v8 = *(const bf16x8*)(src + (size_t)n * QKV3 + d8);
        const int byte = (n * 128 + d8 * 2) ^ (((n >> 3) & 7) << 4);
        *(bf16x8*)((char*)t + byte) = v8;
    }
    __syncthreads();
    #pragma unroll
    for (int it = 0; it < 2; ++it) {
        const int c = it * 256 + threadIdx.x;
        const int d = c >> 3, nc = c & 7;
        bf16x8 o8;
        #pragma unroll
        for (int i = 0; i < 8; ++i) {
            const int n = nc * 8 + i;
            const int byte = (n * 128 + d * 2) ^ ((nc & 7) << 4);
            o8[i] = *(const bf16*)((const char*)t + byte);
        }
        bf16* dstrow = vT + (size_t)bh * DHEAD * SEQ + (size_t)d * SEQ;
        #pragma unroll
        for (int half = 0; half < 2; ++half) {
            const int nb2 = nc * 8 + half * 4;
            const int nabs = n0 + nb2;
            const int off = nb2 & 31;
            const int offp = (((off >> 4) & 1) << 2) | (((off >> 2) & 3) << 3);
            bf16x4 q4 = { o8[half * 4 + 0], o8[half * 4 + 1],
                          o8[half * 4 + 2], o8[half * 4 + 3] };
            *(bf16x4*)(dstrow + (nabs & ~31) + offp) = q4;
        }
    }
}

// ---------------------------------------------------------------------------
// Flash attention v9 = v8 + MF=2 (32 q-rows per wave): every K/V fragment
// read from LDS feeds TWO MFMAs (one per mf) — DS traffic per unit work
// halves (the binding pipe at v8). Grid 512 (2 blocks/CU), VGPR ~110.
// ---------------------------------------------------------------------------
struct AttnState2 { float m[2], l[2]; f32x4 o[2][4]; };

static __device__ __forceinline__ void attn_body2(
    const bf16* __restrict__ Kbuf, const bf16* __restrict__ Vbuf,
    const bf16x8 qf[2][2], int q, int hi, AttnState2& st)
{
    // S^T = K Q^T for both mf: kfrag read ONCE per (kf,ks)
    f32x4 sv[2][4];
    __builtin_amdgcn_s_setprio(1);
    #pragma unroll
    for (int kf = 0; kf < 4; ++kf) {
        f32x4 z = {0.f, 0.f, 0.f, 0.f};
        sv[0][kf] = z; sv[1][kf] = z;
        #pragma unroll
        for (int ks = 0; ks < 2; ++ks) {
            const int row = kf * 16 + q;
            const int bo = (row * 128 + ks * 64 + (hi << 4)) ^ ((row & 7) << 4);
            const bf16x8 kfrag = *(const bf16x8*)((const char*)Kbuf + bo);
            sv[0][kf] = mfma16(kfrag, qf[0][ks], sv[0][kf]);
            sv[1][kf] = mfma16(kfrag, qf[1][ks], sv[1][kf]);
        }
    }
    __builtin_amdgcn_s_setprio(0);

    bf16x8 pb[2][2];
    #pragma unroll
    for (int mf = 0; mf < 2; ++mf) {
        float pmax;
        {
            float a = fmaxf(fmaxf(sv[mf][0][0], sv[mf][0][1]), fmaxf(sv[mf][0][2], sv[mf][0][3]));
            float b2 = fmaxf(fmaxf(sv[mf][1][0], sv[mf][1][1]), fmaxf(sv[mf][1][2], sv[mf][1][3]));
            float c = fmaxf(fmaxf(sv[mf][2][0], sv[mf][2][1]), fmaxf(sv[mf][2][2], sv[mf][2][3]));
            float d = fmaxf(fmaxf(sv[mf][3][0], sv[mf][3][1]), fmaxf(sv[mf][3][2], sv[mf][3][3]));
            pmax = fmaxf(fmaxf(a, b2), fmaxf(c, d));
        }
        pmax = fmaxf(pmax, __shfl_xor(pmax, 16, 64));
        pmax = fmaxf(pmax, __shfl_xor(pmax, 32, 64));

        if (__any(pmax - st.m[mf] > 8.0f)) {
            const float nm = fmaxf(st.m[mf], pmax);
            const float fr = __expf(st.m[mf] - nm);
            st.l[mf] *= fr;
            #pragma unroll
            for (int df = 0; df < 4; ++df) {
                st.o[mf][df][0] *= fr; st.o[mf][df][1] *= fr;
                st.o[mf][df][2] *= fr; st.o[mf][df][3] *= fr;
            }
            st.m[mf] = nm;
        }

        float pv[4][4];
        float rsum = 0.0f;
        #pragma unroll
        for (int kf = 0; kf < 4; ++kf)
            #pragma unroll
            for (int r = 0; r < 4; ++r) {
                pv[kf][r] = __expf(sv[mf][kf][r] - st.m[mf]);
                rsum += pv[kf][r];
            }
        st.l[mf] += rsum;

        #pragma unroll
        for (int ks = 0; ks < 2; ++ks)
            #pragma unroll
            for (int r = 0; r < 4; ++r) {
                pb[mf][ks][r]     = (bf16)pv[2 * ks][r];
                pb[mf][ks][r + 4] = (bf16)pv[2 * ks + 1][r];
            }
    }

    // O^T += V^T P^T : vfrag read ONCE per (df,ks), feeds both mf
    __builtin_amdgcn_s_setprio(1);
    #pragma unroll
    for (int df = 0; df < 4; ++df) {
        const int rowv = df * 16 + q;
        #pragma unroll
        for (int ks = 0; ks < 2; ++ks) {
            const int bo = (rowv * 128 + ks * 64 + (hi << 4)) ^ ((rowv & 7) << 4);
            const bf16x8 vfrag = *(const bf16x8*)((const char*)Vbuf + bo);
            st.o[0][df] = mfma16(vfrag, pb[0][ks], st.o[0][df]);
            st.o[1][df] = mfma16(vfrag, pb[1][ks], st.o[1][df]);
        }
    }
    __builtin_amdgcn_s_setprio(0);
}

__global__ __launch_bounds__(256, 2)
void attn_kernel(const bf16* __restrict__ qkv, const bf16* __restrict__ vT,
                 bf16* __restrict__ out)
{
    __shared__ bf16 Ks[2][64 * 64];
    __shared__ bf16 Vs[2][64 * 64];
    const int bid = blockIdx.x;                   // 0..511
    const int idx = (bid & 7) * 64 + (bid >> 3);  // bijective XCD swizzle
    const int qt = idx & 15;                      // 16 q-tiles of 128 rows
    const int bh = idx >> 4;
    const int b = bh >> 4, h = bh & 15;
    const int tid = threadIdx.x;
    const int lane = tid & 63, wave = tid >> 6;
    const int q = lane & 15, hi = lane >> 4;

    const bf16* qbase = qkv + (size_t)(b * SEQ) * QKV3 + h * DHEAD;
    const bf16* kbase = qbase + DIMM;
    const bf16* vbase = vT + (size_t)bh * DHEAD * SEQ;

    const int q0 = qt * 128 + wave * 32;
    bf16x8 qf[2][2];
    #pragma unroll
    for (int mf = 0; mf < 2; ++mf) {
        const bf16* qp = qbase + (size_t)(q0 + mf * 16 + q) * QKV3 + (hi << 3);
        qf[mf][0] = *(const bf16x8*)qp;
        qf[mf][1] = *(const bf16x8*)(qp + 32);
        #pragma unroll
        for (int j = 0; j < 8; ++j) {
            qf[mf][0][j] = (bf16)((float)qf[mf][0][j] * 0.125f);
            qf[mf][1][j] = (bf16)((float)qf[mf][1][j] * 0.125f);
        }
    }

    const int srow = lane >> 3;
    const int scol = ((lane & 7) ^ srow) << 3;
    const bf16* gk = kbase + (size_t)(wave * 16 + srow) * QKV3 + scol;
    const bf16* gv = vbase + (size_t)(wave * 16 + srow) * SEQ + scol;

#define STAGE(BUF, KT) do {                                        \
        bf16* lk_ = &Ks[BUF][wave * 1024];                         \
        bf16* lv_ = &Vs[BUF][wave * 1024];                         \
        GLDS16(gk + (size_t)(KT) * QKV3,       lk_);               \
        GLDS16(gk + (size_t)((KT) + 8) * QKV3, lk_ + 512);         \
        GLDS16(gv + (KT),                      lv_);               \
        GLDS16(gv + (KT) + 8 * SEQ,            lv_ + 512);         \
    } while (0)

    AttnState2 st;
    #pragma unroll
    for (int mf = 0; mf < 2; ++mf) {
        st.m[mf] = -1e30f; st.l[mf] = 0.0f;
        #pragma unroll
        for (int df = 0; df < 4; ++df) {
            f32x4 z = {0.f, 0.f, 0.f, 0.f};
            st.o[mf][df] = z;
        }
    }

    STAGE(0, 0);
    for (int kt = 0; kt < SEQ; kt += 128) {
        __syncthreads();                       // STAGE(kt) resident
        STAGE(1, kt + 64);
        attn_body2(&Ks[0][0], &Vs[0][0], qf, q, hi, st);
        __syncthreads();                       // STAGE(kt+64) resident
        if (kt + 128 < SEQ) STAGE(0, kt + 128);
        attn_body2(&Ks[1][0], &Vs[1][0], qf, q, hi, st);
    }
#undef STAGE

    #pragma unroll
    for (int mf = 0; mf < 2; ++mf) {
        float lt = st.l[mf];
        lt += __shfl_xor(lt, 16, 64);
        lt += __shfl_xor(lt, 32, 64);
        const float inv = 1.0f / lt;
        const int grow = b * SEQ + q0 + mf * 16 + q;
        #pragma unroll
        for (int df = 0; df < 4; ++df) {
            bf16x4 pk = { (bf16)(st.o[mf][df][0] * inv), (bf16)(st.o[mf][df][1] * inv),
                          (bf16)(st.o[mf][df][2] * inv), (bf16)(st.o[mf][df][3] * inv) };
            *(bf16x4*)(out + (size_t)grow * DIMM + h * DHEAD + df * 16 + hi * 4) = pk;
        }
    }
}

// ---------------------------------------------------------------------------
extern "C" void kernel_launch(void* const* d_in, const int* in_sizes, int n_in,
                              void* d_out, int out_size, void* d_ws, size_t ws_size,
                              hipStream_t stream)
{
    (void)in_sizes; (void)n_in; (void)out_size;
    const float* x    = (const float*)d_in[0];
    const float* ln1g = (const float*)d_in[1];
    const float* ln1b = (const float*)d_in[2];
    const float* ln2g = (const float*)d_in[3];
    const float* ln2b = (const float*)d_in[4];
    const float* wqkv = (const float*)d_in[5];
    const float* wout = (const float*)d_in[6];
    const float* bout = (const float*)d_in[7];
    const float* wff1 = (const float*)d_in[8];
    const float* bff1 = (const float*)d_in[9];
    const float* wff2 = (const float*)d_in[10];
    const float* bff2 = (const float*)d_in[11];

    char* ws = (char*)d_ws;
    const dim3 blk(256);
    const dim3 blk512(512);
    const bool splitk = ws_size >= 92274688ULL;   // 88 MB packed layout

    if (splitk) {
        bf16*  wff2T = (bf16*)(ws);
        bf16*  woutT = (bf16*)(ws + 8388608);
        bf16*  wff1T = (bf16*)(ws + 10485760);
        bf16*  wqkvT = (bf16*)(ws + 18874368);
        bf16*  hbuf  = (bf16*)(ws + 25165824);
        bf16*  qkvb  = (bf16*)(ws + 33554432);
        bf16*  vT    = (bf16*)(ws + 58720256);
        bf16*  attnb = (bf16*)(ws + 67108864);
        float* x2    = (float*)(ws + 75497472);
        bf16*  fbuf  = (bf16*)(ws + 41943040);
        float* p0    = (float*)(ws + 8388608);
        float* p1    = (float*)(ws + 25165824);

        wcast_kernel<<<dim3(12288), blk, 0, stream>>>(
            wqkv, wqkvT, wout, woutT, wff1, wff1T, wff2, wff2T);

        ln_cast_kernel<<<NROWS, blk, 0, stream>>>(x, ln1g, ln1b, hbuf);
        gemm_bt_kernel<0><<<(NROWS / 128) * (QKV3 / 128), blk, 0, stream>>>(
            hbuf, wqkvT, nullptr, nullptr, qkvb, NROWS, QKV3, DIMM, DIMM);
        vtrans_kernel<<<dim3(SEQ / 64, BATCH * NHEAD), blk, 0, stream>>>(qkvb, vT);
        attn_kernel<<<dim3(512), blk, 0, stream>>>(qkvb, vT, attnb);
        gemm_bt_kernel<1><<<(NROWS / 128) * (DIMM / 128), blk, 0, stream>>>(
            attnb, woutT, bout, x, x2, NROWS, DIMM, DIMM, DIMM);
        ln_cast_kernel<<<NROWS, blk, 0, stream>>>(x2, ln2g, ln2b, hbuf);
        gemm256_kernel<2><<<(NROWS / 256) * (FFD / 256), blk512, 0, stream>>>(
            hbuf, wff1T, bff1, fbuf, NROWS, FFD, DIMM, DIMM);
        gemm_bt_kernel<3><<<2 * (NROWS / 128) * (DIMM / 128), blk, 0, stream>>>(
            fbuf, wff2T, nullptr, (const float*)p1, p0, NROWS, DIMM, FFD / 2, FFD);
        ff2_reduce_kernel<<<(NROWS * DIMM) / 1024, blk, 0, stream>>>(
            p0, p1, bff2, x2, (float*)d_out);
    } else {
        bf16*  wqkvT = (bf16*)(ws);
        bf16*  woutT = (bf16*)(ws + 6291456);
        bf16*  wff1T = (bf16*)(ws + 8388608);
        bf16*  wff2T = (bf16*)(ws + 16777216);
        float* x2    = (float*)(ws + 25165824);
        bf16*  vT    = (bf16*)(ws + 25165824);
        bf16*  hbuf  = (bf16*)(ws + 41943040);
        bf16*  qkvb  = (bf16*)(ws + 50331648);
        bf16*  attnb = (bf16*)(ws + 75497472);
        bf16*  fbuf  = (bf16*)(ws + 50331648);

        wcast_kernel<<<dim3(12288), blk, 0, stream>>>(
            wqkv, wqkvT, wout, woutT, wff1, wff1T, wff2, wff2T);

        ln_cast_kernel<<<NROWS, blk, 0, stream>>>(x, ln1g, ln1b, hbuf);
        gemm_bt_kernel<0><<<(NROWS / 128) * (QKV3 / 128), blk, 0, stream>>>(
            hbuf, wqkvT, nullptr, nullptr, qkvb, NROWS, QKV3, DIMM, DIMM);
        vtrans_kernel<<<dim3(SEQ / 64, BATCH * NHEAD), blk, 0, stream>>>(qkvb, vT);
        attn_kernel<<<dim3(512), blk, 0, stream>>>(qkvb, vT, attnb);
        gemm_bt_kernel<1><<<(NROWS / 128) * (DIMM / 128), blk, 0, stream>>>(
            attnb, woutT, bout, x, x2, NROWS, DIMM, DIMM, DIMM);
        ln_cast_kernel<<<NROWS, blk, 0, stream>>>(x2, ln2g, ln2b, hbuf);
        gemm256_kernel<2><<<(NROWS / 256) * (FFD / 256), blk512, 0, stream>>>(
            hbuf, wff1T, bff1, fbuf, NROWS, FFD, DIMM, DIMM);
        gemm_bt_kernel<1><<<(NROWS / 128) * (DIMM / 128), blk, 0, stream>>>(
            fbuf, wff2T, bff2, x2, (float*)d_out, NROWS, DIMM, FFD, FFD);
    }
}

// Round 21
// 254.768 us; speedup vs baseline: 1.0039x; 1.0039x over previous
//
#include <hip/hip_runtime.h>
#include <hip/hip_bf16.h>
#include <math.h>

#define SEQ   2048
#define BATCH 2
#define NROWS 4096      /* BATCH*SEQ */
#define DIMM  1024
#define QKV3  3072
#define FFD   4096
#define NHEAD 16
#define DHEAD 64

typedef __bf16 bf16;
typedef __bf16 bf16x4 __attribute__((ext_vector_type(4)));
typedef __bf16 bf16x8 __attribute__((ext_vector_type(8)));
typedef float  f32x4  __attribute__((ext_vector_type(4)));

static __device__ __forceinline__ f32x4 mfma16(bf16x8 a, bf16x8 b, f32x4 c) {
    return __builtin_amdgcn_mfma_f32_16x16x32_bf16(a, b, c, 0, 0, 0);
}

#define GLDS16(gp, lp) __builtin_amdgcn_global_load_lds( \
    (__attribute__((address_space(1))) void*)(gp),       \
    (__attribute__((address_space(3))) void*)(lp), 16, 0, 0)

#define MEMFENCE asm volatile("" ::: "memory")

// ---------------------------------------------------------------------------
// Merged weight transpose+cast: all 4 matrices in ONE launch.
//   tiles: wqkv 3072 | wout 1024 | wff1 4096 | wff2 4096  (total 12288)
// ---------------------------------------------------------------------------
__global__ __launch_bounds__(256) void wcast_kernel(
    const float* __restrict__ wqkv, bf16* __restrict__ wqkvT,
    const float* __restrict__ wout, bf16* __restrict__ woutT,
    const float* __restrict__ wff1, bf16* __restrict__ wff1T,
    const float* __restrict__ wff2, bf16* __restrict__ wff2T)
{
    int t = blockIdx.x;
    const float* src; bf16* dst; int K, N, nx;
    if (t < 3072)      { src = wqkv; dst = wqkvT; K = DIMM; N = QKV3; nx = 96;  }
    else if (t < 4096) { src = wout; dst = woutT; K = DIMM; N = DIMM; nx = 32; t -= 3072; }
    else if (t < 8192) { src = wff1; dst = wff1T; K = DIMM; N = FFD;  nx = 128; t -= 4096; }
    else               { src = wff2; dst = wff2T; K = FFD;  N = DIMM; nx = 32; t -= 8192; }
    const int k0 = (t / nx) * 32;
    const int n0 = (t - (t / nx) * nx) * 32;

    __shared__ float tile[32][33];
    const int r = threadIdx.x >> 5;   // 0..7
    const int c = threadIdx.x & 31;
    #pragma unroll
    for (int i = 0; i < 4; ++i)
        tile[r + 8 * i][c] = src[(size_t)(k0 + r + 8 * i) * N + n0 + c];
    __syncthreads();
    #pragma unroll
    for (int i = 0; i < 4; ++i)
        dst[(size_t)(n0 + r + 8 * i) * K + k0 + c] = (bf16)tile[c][r + 8 * i];
}

// ---------------------------------------------------------------------------
// LayerNorm fp32 [NROWS][1024] -> bf16, one block per row
// ---------------------------------------------------------------------------
__global__ __launch_bounds__(256) void ln_cast_kernel(
    const float* __restrict__ x, const float* __restrict__ g,
    const float* __restrict__ b, bf16* __restrict__ out)
{
    const int row = blockIdx.x;
    const int t = threadIdx.x;
    const float4 v = ((const float4*)(x + (size_t)row * DIMM))[t];
    float s  = v.x + v.y + v.z + v.w;
    float sq = v.x * v.x + v.y * v.y + v.z * v.z + v.w * v.w;
    #pragma unroll
    for (int m = 1; m < 64; m <<= 1) {
        s  += __shfl_xor(s, m, 64);
        sq += __shfl_xor(sq, m, 64);
    }
    __shared__ float ss[4], ssq[4];
    const int wave = t >> 6;
    if ((t & 63) == 0) { ss[wave] = s; ssq[wave] = sq; }
    __syncthreads();
    s  = ss[0] + ss[1] + ss[2] + ss[3];
    sq = ssq[0] + ssq[1] + ssq[2] + ssq[3];
    const float mean = s * (1.0f / DIMM);
    const float var  = sq * (1.0f / DIMM) - mean * mean;
    const float rs   = rsqrtf(var + 1e-5f);
    const float4 gv = ((const float4*)g)[t];
    const float4 bv = ((const float4*)b)[t];
    bf16* o = out + (size_t)row * DIMM + t * 4;
    o[0] = (bf16)((v.x - mean) * rs * gv.x + bv.x);
    o[1] = (bf16)((v.y - mean) * rs * gv.y + bv.y);
    o[2] = (bf16)((v.z - mean) * rs * gv.z + bv.z);
    o[3] = (bf16)((v.w - mean) * rs * gv.w + bv.w);
}

// ---------------------------------------------------------------------------
// 256x256 8-wave GEMM — 4-phase fine-interleaved schedule (r13/r14 proven).
// Used for FF1 only (grid 256 = exactly 1 block/CU).
// EPI: 2 = +bias, GELU, bf16 out
// ---------------------------------------------------------------------------
template<int EPI>
__global__ __launch_bounds__(512, 2)
void gemm256_kernel(const bf16* __restrict__ A, const bf16* __restrict__ BT,
                    const float* __restrict__ bias, bf16* __restrict__ C,
                    int M, int N, int K, int ld)
{
    __shared__ bf16 As_[2][2][8192];   // [dbuf][half][128 rows x 64 k]
    __shared__ bf16 Bs_[2][2][8192];
    const int nb = N >> 8;
    const int chunk = (int)gridDim.x >> 3;
    const int idx = ((int)blockIdx.x & 7) * chunk + ((int)blockIdx.x >> 3);
    const int bm = idx / nb, bn = idx - bm * nb;
    const int tm = bm << 8, tn = bn << 8;
    const int tid = threadIdx.x;
    const int lane = tid & 63, w = tid >> 6;   // 8 waves
    const int wr = w >> 2, wc = w & 3;
    const int lq = lane & 15, hk = lane >> 4;

    const int sr  = lane >> 3;
    const int sgo = (((lane & 7) ^ sr) << 3);
    const bf16* gA0 = A  + (size_t)(tm +       w * 8 + sr) * ld + sgo;
    const bf16* gA1 = A  + (size_t)(tm + 128 + w * 8 + sr) * ld + sgo;
    const bf16* gB0 = BT + (size_t)(tn +       w * 8 + sr) * ld + sgo;
    const bf16* gB1 = BT + (size_t)(tn + 128 + w * 8 + sr) * ld + sgo;
    const size_t l64 = (size_t)64 * ld;

#define STG_A0(D, T) do { const size_t ko_ = (size_t)(T) * 64;              \
        GLDS16(gA0 + ko_,       &As_[D][0][w * 512]);                       \
        GLDS16(gA0 + ko_ + l64, &As_[D][0][4096 + w * 512]); } while (0)
#define STG_A1(D, T) do { const size_t ko_ = (size_t)(T) * 64;              \
        GLDS16(gA1 + ko_,       &As_[D][1][w * 512]);                       \
        GLDS16(gA1 + ko_ + l64, &As_[D][1][4096 + w * 512]); } while (0)
#define STG_B0(D, T) do { const size_t ko_ = (size_t)(T) * 64;              \
        GLDS16(gB0 + ko_,       &Bs_[D][0][w * 512]);                       \
        GLDS16(gB0 + ko_ + l64, &Bs_[D][0][4096 + w * 512]); } while (0)
#define STG_B1(D, T) do { const size_t ko_ = (size_t)(T) * 64;              \
        GLDS16(gB1 + ko_,       &Bs_[D][1][w * 512]);                       \
        GLDS16(gB1 + ko_ + l64, &Bs_[D][1][4096 + w * 512]); } while (0)

    f32x4 acc[8][4] = {};
    const int NT = K >> 6;

    STG_A0(0, 0); STG_B1(0, 0); STG_B0(0, 0); STG_A1(0, 0);
    STG_B0(1, 1); STG_A1(1, 1);

    for (int t = 0; t < NT; ++t) {
        const int d = t & 1, e = d ^ 1;
        if (t == NT - 1) asm volatile("s_waitcnt vmcnt(0)" ::: "memory");
        else             asm volatile("s_waitcnt vmcnt(4)" ::: "memory");
        __builtin_amdgcn_s_barrier();
        MEMFENCE;

        const char* Ah0 = (const char*)&As_[d][0][0];
        const char* Ah1 = (const char*)&As_[d][1][0];
        const char* Bh0 = (const char*)&Bs_[d][0][0];
        const char* Bh1 = (const char*)&Bs_[d][1][0];
        bf16x8 af[4][2], bfv[2][2];

#define DO_MFMA(MH, NH) do {                                                 \
        __builtin_amdgcn_s_setprio(1);                                       \
        _Pragma("unroll")                                                    \
        for (int mi = 0; mi < 4; ++mi)                                       \
            _Pragma("unroll")                                                \
            for (int nj = 0; nj < 2; ++nj)                                   \
                _Pragma("unroll")                                            \
                for (int kk = 0; kk < 2; ++kk)                               \
                    acc[(MH)*4+mi][(NH)*2+nj] =                              \
                        mfma16(bfv[nj][kk], af[mi][kk], acc[(MH)*4+mi][(NH)*2+nj]); \
        __builtin_amdgcn_s_setprio(0); } while (0)

        {   // ph1 (0,0)
            #pragma unroll
            for (int mi = 0; mi < 4; ++mi) {
                const int lr = wr * 64 + mi * 16 + lq;
                af[mi][0] = *(const bf16x8*)(Ah0 + lr * 128 + ((hk ^ (lr & 7)) << 4));
                af[mi][1] = *(const bf16x8*)(Ah0 + lr * 128 + (((4 + hk) ^ (lr & 7)) << 4));
            }
            #pragma unroll
            for (int nj = 0; nj < 2; ++nj) {
                const int lc = wc * 32 + nj * 16 + lq;
                bfv[nj][0] = *(const bf16x8*)(Bh0 + lc * 128 + ((hk ^ (lc & 7)) << 4));
                bfv[nj][1] = *(const bf16x8*)(Bh0 + lc * 128 + (((4 + hk) ^ (lc & 7)) << 4));
            }
            if (t + 1 < NT) STG_A0(e, t + 1);
            DO_MFMA(0, 0);
        }
        MEMFENCE; __builtin_amdgcn_s_barrier(); MEMFENCE;
        {   // ph2 (1,0)
            #pragma unroll
            for (int mi = 0; mi < 4; ++mi) {
                const int lr = wr * 64 + mi * 16 + lq;
                af[mi][0] = *(const bf16x8*)(Ah1 + lr * 128 + ((hk ^ (lr & 7)) << 4));
                af[mi][1] = *(const bf16x8*)(Ah1 + lr * 128 + (((4 + hk) ^ (lr & 7)) << 4));
            }
            if (t + 1 < NT) STG_B1(e, t + 1);
            DO_MFMA(1, 0);
        }
        MEMFENCE; __builtin_amdgcn_s_barrier(); MEMFENCE;
        {   // ph3 (1,1)
            #pragma unroll
            for (int nj = 0; nj < 2; ++nj) {
                const int lc = wc * 32 + nj * 16 + lq;
                bfv[nj][0] = *(const bf16x8*)(Bh1 + lc * 128 + ((hk ^ (lc & 7)) << 4));
                bfv[nj][1] = *(const bf16x8*)(Bh1 + lc * 128 + (((4 + hk) ^ (lc & 7)) << 4));
            }
            if (t + 2 < NT) STG_B0(d, t + 2);
            DO_MFMA(1, 1);
        }
        MEMFENCE; __builtin_amdgcn_s_barrier(); MEMFENCE;
        {   // ph4 (0,1)
            #pragma unroll
            for (int mi = 0; mi < 4; ++mi) {
                const int lr = wr * 64 + mi * 16 + lq;
                af[mi][0] = *(const bf16x8*)(Ah0 + lr * 128 + ((hk ^ (lr & 7)) << 4));
                af[mi][1] = *(const bf16x8*)(Ah0 + lr * 128 + (((4 + hk) ^ (lr & 7)) << 4));
            }
            if (t + 2 < NT) STG_A1(d, t + 2);
            DO_MFMA(0, 1);
        }
        MEMFENCE; __builtin_amdgcn_s_barrier(); MEMFENCE;
#undef DO_MFMA
    }
#undef STG_A0
#undef STG_A1
#undef STG_B0
#undef STG_B1

    #pragma unroll
    for (int i = 0; i < 8; ++i) {
        const int mh = i >> 2, mi = i & 3;
        const int row = tm + mh * 128 + wr * 64 + mi * 16 + lq;
        #pragma unroll
        for (int j = 0; j < 4; ++j) {
            const int nh = j >> 1, nj = j & 1;
            const int col = tn + nh * 128 + wc * 32 + nj * 16 + (hk << 2);
            if (EPI == 0) {
                bf16x4 pk = { (bf16)acc[i][j][0], (bf16)acc[i][j][1],
                              (bf16)acc[i][j][2], (bf16)acc[i][j][3] };
                *(bf16x4*)(C + (size_t)row * N + col) = pk;
            } else {
                const float4 bv4 = *(const float4*)(bias + col);
                float v0 = acc[i][j][0] + bv4.x, v1 = acc[i][j][1] + bv4.y;
                float v2 = acc[i][j][2] + bv4.z, v3 = acc[i][j][3] + bv4.w;
                bf16x4 pk = {
                    (bf16)(0.5f * v0 * (1.0f + erff(v0 * 0.70710678118654752f))),
                    (bf16)(0.5f * v1 * (1.0f + erff(v1 * 0.70710678118654752f))),
                    (bf16)(0.5f * v2 * (1.0f + erff(v2 * 0.70710678118654752f))),
                    (bf16)(0.5f * v3 * (1.0f + erff(v3 * 0.70710678118654752f))) };
                *(bf16x4*)(C + (size_t)row * N + col) = pk;
            }
        }
    }
}

// ---------------------------------------------------------------------------
// 128x128 3-stage counted-vmcnt GEMM + swapped-operand vectorized epilogue.
// Used for QKV (768 blk, 3/CU), out-proj, FF2 split-K.
// EPI: 0 = bf16 out; 1 = +bias +residual, fp32 out; 3 = split-K partial
// ---------------------------------------------------------------------------
template<int EPI>
__global__ __launch_bounds__(256, 3)
void gemm_bt_kernel(const bf16* __restrict__ A, const bf16* __restrict__ BT,
                    const float* __restrict__ bias, const float* __restrict__ res,
                    void* __restrict__ Cout, int M, int N, int K, int ld)
{
    __shared__ bf16 As[3][4096];   // [buf][128 m][32 k]
    __shared__ bf16 Bs[3][4096];
    const int nb = N >> 7;
    const int chunk = (int)gridDim.x >> 3;
    int idx = (blockIdx.x & 7) * chunk + (blockIdx.x >> 3);
    int ks = 0;
    if (EPI == 3) {
        const int tiles = (M >> 7) * nb;
        ks = idx / tiles;
        idx -= ks * tiles;
    }
    const int bm = idx / nb, bn = idx - bm * nb;
    const int tm = bm << 7, tn = bn << 7;
    const int tid = threadIdx.x;
    const int lane = tid & 63, wave = tid >> 6;
    const int wm = (wave >> 1) << 6, wn = (wave & 1) << 6;
    const int kofs = ks * K;

    const bf16* ga = A  + (size_t)(tm + wave * 32 + (lane >> 2)) * ld + kofs + ((lane & 3) << 3);
    const bf16* gb = BT + (size_t)(tn + wave * 32 + (lane >> 2)) * ld + kofs + ((lane & 3) << 3);
    const size_t k16 = (size_t)16 * ld;

    f32x4 acc[4][4] = {};
    const int ro = (lane & 15) * 32 + ((lane >> 4) << 3);

#define GSTAGE(BUF, KO) do {                          \
        bf16* la_ = &As[BUF][wave * 1024];            \
        bf16* lb_ = &Bs[BUF][wave * 1024];            \
        GLDS16(ga + (KO),       la_);                 \
        GLDS16(ga + (KO) + k16, la_ + 512);           \
        GLDS16(gb + (KO),       lb_);                 \
        GLDS16(gb + (KO) + k16, lb_ + 512);           \
    } while (0)

    GSTAGE(0, 0);
    GSTAGE(1, 32);
    GSTAGE(2, 64);
    int cur = 0;
    for (int k0 = 0; k0 < K; k0 += 32) {
        if (k0 + 96 <= K)      asm volatile("s_waitcnt vmcnt(8)" ::: "memory");
        else if (k0 + 64 <= K) asm volatile("s_waitcnt vmcnt(4)" ::: "memory");
        else                   asm volatile("s_waitcnt vmcnt(0)" ::: "memory");
        __builtin_amdgcn_s_barrier();

        bf16x8 af[4], bfr[4];
        #pragma unroll
        for (int i = 0; i < 4; ++i) {
            af[i]  = *(const bf16x8*)(&As[cur][0] + (wm + i * 16) * 32 + ro);
            bfr[i] = *(const bf16x8*)(&Bs[cur][0] + (wn + i * 16) * 32 + ro);
        }
        #pragma unroll
        for (int i = 0; i < 4; ++i)
            #pragma unroll
            for (int j = 0; j < 4; ++j)
                acc[i][j] = mfma16(bfr[j], af[i], acc[i][j]);   // swapped

        MEMFENCE;
        __builtin_amdgcn_s_barrier();
        MEMFENCE;
        if (k0 + 96 < K) GSTAGE(cur, k0 + 96);
        cur = (cur == 2) ? 0 : cur + 1;
    }
#undef GSTAGE

    // swapped layout: acc[i][j][r] = C[tm+wm+i*16+lq][tn+wn+j*16+hk*4+r]
    const int lq = lane & 15, hk = lane >> 4;
    const int r0 = tm + wm + lq;
    const int c0 = tn + wn + (hk << 2);
    if (EPI == 0) {
        bf16* C = (bf16*)Cout;
        #pragma unroll
        for (int j = 0; j < 4; ++j)
            #pragma unroll
            for (int i = 0; i < 4; ++i) {
                bf16x4 pk = { (bf16)acc[i][j][0], (bf16)acc[i][j][1],
                              (bf16)acc[i][j][2], (bf16)acc[i][j][3] };
                *(bf16x4*)(C + (size_t)(r0 + i * 16) * N + c0 + j * 16) = pk;
            }
    } else if (EPI == 1) {
        float* C = (float*)Cout;
        #pragma unroll
        for (int j = 0; j < 4; ++j) {
            const float4 bv4 = *(const float4*)(bias + c0 + j * 16);
            #pragma unroll
            for (int i = 0; i < 4; ++i) {
                const size_t off = (size_t)(r0 + i * 16) * N + c0 + j * 16;
                const float4 rv = *(const float4*)(res + off);
                float4 o;
                o.x = acc[i][j][0] + bv4.x + rv.x;
                o.y = acc[i][j][1] + bv4.y + rv.y;
                o.z = acc[i][j][2] + bv4.z + rv.z;
                o.w = acc[i][j][3] + bv4.w + rv.w;
                *(float4*)(C + off) = o;
            }
        }
    } else {
        float* C = (float*)(ks == 0 ? Cout : (void*)res);
        #pragma unroll
        for (int j = 0; j < 4; ++j)
            #pragma unroll
            for (int i = 0; i < 4; ++i) {
                float4 o = { acc[i][j][0], acc[i][j][1], acc[i][j][2], acc[i][j][3] };
                *(float4*)(C + (size_t)(r0 + i * 16) * N + c0 + j * 16) = o;
            }
    }
}

// ---------------------------------------------------------------------------
// FF2 split-K reduce: out = p0 + p1 + bias + res  (all fp32, [NROWS][DIMM])
// ---------------------------------------------------------------------------
__global__ __launch_bounds__(256) void ff2_reduce_kernel(
    const float* __restrict__ p0, const float* __restrict__ p1,
    const float* __restrict__ bias, const float* __restrict__ res,
    float* __restrict__ out)
{
    const int i = blockIdx.x * 256 + threadIdx.x;    // float4 index
    const float4 a = ((const float4*)p0)[i];
    const float4 b = ((const float4*)p1)[i];
    const float4 r = ((const float4*)res)[i];
    const float4 g = ((const float4*)bias)[i & 255];
    float4 o;
    o.x = a.x + b.x + r.x + g.x;
    o.y = a.y + b.y + r.y + g.y;
    o.z = a.z + b.z + r.z + g.z;
    o.w = a.w + b.w + r.w + g.w;
    ((float4*)out)[i] = o;
}

// ---------------------------------------------------------------------------
// V transpose per head, PERMUTED columns (r18 proven): within each 32-column
// block, position n' holds V column n with
//   n' = (n&3) | ((n>>4)&1)<<2 | ((n>>2)&3)<<3
// ---------------------------------------------------------------------------
__global__ __launch_bounds__(256) void vtrans_kernel(
    const bf16* __restrict__ qkv, bf16* __restrict__ vT)
{
    __shared__ bf16 t[64 * 64];
    const int n0 = blockIdx.x * 64;
    const int bh = blockIdx.y;
    const int b = bh >> 4, h = bh & 15;
    const bf16* src = qkv + (size_t)(b * SEQ + n0) * QKV3 + 2 * DIMM + h * DHEAD;

    #pragma unroll
    for (int it = 0; it < 2; ++it) {
        const int c = it * 256 + threadIdx.x;
        const int n = c >> 3, d8 = (c & 7) * 8;
        const bf16x8 v8 = *(const bf16x8*)(src + (size_t)n * QKV3 + d8);
        const int byte = (n * 128 + d8 * 2) ^ (((n >> 3) & 7) << 4);
        *(bf16x8*)((char*)t + byte) = v8;
    }
    __syncthreads();
    #pragma unroll
    for (int it = 0; it < 2; ++it) {
        const int c = it * 256 + threadIdx.x;
        const int d = c >> 3, nc = c & 7;
        bf16x8 o8;
        #pragma unroll
        for (int i = 0; i < 8; ++i) {
            const int n = nc * 8 + i;
            const int byte = (n * 128 + d * 2) ^ ((nc & 7) << 4);
            o8[i] = *(const bf16*)((const char*)t + byte);
        }
        bf16* dstrow = vT + (size_t)bh * DHEAD * SEQ + (size_t)d * SEQ;
        #pragma unroll
        for (int half = 0; half < 2; ++half) {
            const int nb2 = nc * 8 + half * 4;
            const int nabs = n0 + nb2;
            const int off = nb2 & 31;
            const int offp = (((off >> 4) & 1) << 2) | (((off >> 2) & 3) << 3);
            bf16x4 q4 = { o8[half * 4 + 0], o8[half * 4 + 1],
                          o8[half * 4 + 2], o8[half * 4 + 3] };
            *(bf16x4*)(dstrow + (nabs & ~31) + offp) = q4;
        }
    }
}

// ---------------------------------------------------------------------------
// Flash attention v8 (r19-proven, 61.4 us — best): P-in-register PV with
// permuted vT', 2x unrolled K-loop (compile-time buffer indices), lane-local
// l with epilogue reduction. MF=2 experiment (r20) REVERTED: halved occupancy
// cost more than the DS savings gained.
// ---------------------------------------------------------------------------
struct AttnState { float m, l; f32x4 o[4]; };

static __device__ __forceinline__ void attn_body(
    const bf16* __restrict__ Kbuf, const bf16* __restrict__ Vbuf,
    const bf16x8* __restrict__ qf, int q, int hi, AttnState& st)
{
    // S^T = K Q^T : sv[kf][r] = S[kv=kf*16+hi*4+r][q]
    f32x4 sv[4];
    __builtin_amdgcn_s_setprio(1);
    #pragma unroll
    for (int kf = 0; kf < 4; ++kf) {
        f32x4 z = {0.f, 0.f, 0.f, 0.f};
        sv[kf] = z;
        #pragma unroll
        for (int ks = 0; ks < 2; ++ks) {
            const int row = kf * 16 + q;
            const int bo = (row * 128 + ks * 64 + (hi << 4)) ^ ((row & 7) << 4);
            const bf16x8 kfrag = *(const bf16x8*)((const char*)Kbuf + bo);
            sv[kf] = mfma16(kfrag, qf[ks], sv[kf]);
        }
    }
    __builtin_amdgcn_s_setprio(0);

    float pmax;
    {
        float a = fmaxf(fmaxf(sv[0][0], sv[0][1]), fmaxf(sv[0][2], sv[0][3]));
        float b2 = fmaxf(fmaxf(sv[1][0], sv[1][1]), fmaxf(sv[1][2], sv[1][3]));
        float c = fmaxf(fmaxf(sv[2][0], sv[2][1]), fmaxf(sv[2][2], sv[2][3]));
        float d = fmaxf(fmaxf(sv[3][0], sv[3][1]), fmaxf(sv[3][2], sv[3][3]));
        pmax = fmaxf(fmaxf(a, b2), fmaxf(c, d));
    }
    pmax = fmaxf(pmax, __shfl_xor(pmax, 16, 64));
    pmax = fmaxf(pmax, __shfl_xor(pmax, 32, 64));

    if (__any(pmax - st.m > 8.0f)) {
        const float nm = fmaxf(st.m, pmax);
        const float fr = __expf(st.m - nm);
        st.l *= fr;
        #pragma unroll
        for (int df = 0; df < 4; ++df) {
            st.o[df][0] *= fr; st.o[df][1] *= fr;
            st.o[df][2] *= fr; st.o[df][3] *= fr;
        }
        st.m = nm;
    }

    // P = exp(S - m), lane-local l accumulation (reduced in epilogue)
    float pv[4][4];
    float rsum = 0.0f;
    #pragma unroll
    for (int kf = 0; kf < 4; ++kf)
        #pragma unroll
        for (int r = 0; r < 4; ++r) {
            pv[kf][r] = __expf(sv[kf][r] - st.m);
            rsum += pv[kf][r];
        }
    st.l += rsum;

    // pack P into PV B-operands (permuted-k)
    bf16x8 pb[2];
    #pragma unroll
    for (int ks = 0; ks < 2; ++ks)
        #pragma unroll
        for (int r = 0; r < 4; ++r) {
            pb[ks][r]     = (bf16)pv[2 * ks][r];
            pb[ks][r + 4] = (bf16)pv[2 * ks + 1][r];
        }

    // O^T += V^T P^T : conflict-free b128 A-read (permutation baked in vT')
    __builtin_amdgcn_s_setprio(1);
    #pragma unroll
    for (int df = 0; df < 4; ++df) {
        const int rowv = df * 16 + q;
        #pragma unroll
        for (int ks = 0; ks < 2; ++ks) {
            const int bo = (rowv * 128 + ks * 64 + (hi << 4)) ^ ((rowv & 7) << 4);
            const bf16x8 vfrag = *(const bf16x8*)((const char*)Vbuf + bo);
            st.o[df] = mfma16(vfrag, pb[ks], st.o[df]);
        }
    }
    __builtin_amdgcn_s_setprio(0);
}

__global__ __launch_bounds__(256, 4)
void attn_kernel(const bf16* __restrict__ qkv, const bf16* __restrict__ vT,
                 bf16* __restrict__ out)
{
    __shared__ bf16 Ks[2][64 * 64];
    __shared__ bf16 Vs[2][64 * 64];
    const int bid = blockIdx.x;
    const int idx = (bid & 7) * 128 + (bid >> 3);
    const int qt = idx & 31;
    const int bh = idx >> 5;
    const int b = bh >> 4, h = bh & 15;
    const int tid = threadIdx.x;
    const int lane = tid & 63, wave = tid >> 6;
    const int q = lane & 15, hi = lane >> 4;

    const bf16* qbase = qkv + (size_t)(b * SEQ) * QKV3 + h * DHEAD;
    const bf16* kbase = qbase + DIMM;
    const bf16* vbase = vT + (size_t)bh * DHEAD * SEQ;

    const int q0 = qt * 64 + wave * 16;
    bf16x8 qf[2];
    {
        const bf16* qp = qbase + (size_t)(q0 + q) * QKV3 + (hi << 3);
        qf[0] = *(const bf16x8*)qp;
        qf[1] = *(const bf16x8*)(qp + 32);
        #pragma unroll
        for (int j = 0; j < 8; ++j) {
            qf[0][j] = (bf16)((float)qf[0][j] * 0.125f);
            qf[1][j] = (bf16)((float)qf[1][j] * 0.125f);
        }
    }

    const int srow = lane >> 3;
    const int scol = ((lane & 7) ^ srow) << 3;
    const bf16* gk = kbase + (size_t)(wave * 16 + srow) * QKV3 + scol;
    const bf16* gv = vbase + (size_t)(wave * 16 + srow) * SEQ + scol;

#define STAGE(BUF, KT) do {                                        \
        bf16* lk_ = &Ks[BUF][wave * 1024];                         \
        bf16* lv_ = &Vs[BUF][wave * 1024];                         \
        GLDS16(gk + (size_t)(KT) * QKV3,       lk_);               \
        GLDS16(gk + (size_t)((KT) + 8) * QKV3, lk_ + 512);         \
        GLDS16(gv + (KT),                      lv_);               \
        GLDS16(gv + (KT) + 8 * SEQ,            lv_ + 512);         \
    } while (0)

    AttnState st;
    st.m = -1e30f; st.l = 0.0f;
    #pragma unroll
    for (int df = 0; df < 4; ++df) {
        f32x4 z = {0.f, 0.f, 0.f, 0.f};
        st.o[df] = z;
    }

    STAGE(0, 0);
    for (int kt = 0; kt < SEQ; kt += 128) {
        __syncthreads();                       // drains: STAGE(kt) resident
        STAGE(1, kt + 64);                     // always in range (kt+64 <= SEQ-64)
        attn_body(&Ks[0][0], &Vs[0][0], qf, q, hi, st);
        __syncthreads();                       // drains: STAGE(kt+64) resident
        if (kt + 128 < SEQ) STAGE(0, kt + 128);
        attn_body(&Ks[1][0], &Vs[1][0], qf, q, hi, st);
    }
#undef STAGE

    {
        float lt = st.l;
        lt += __shfl_xor(lt, 16, 64);
        lt += __shfl_xor(lt, 32, 64);
        const float inv = 1.0f / lt;
        const int grow = b * SEQ + q0 + q;
        #pragma unroll
        for (int df = 0; df < 4; ++df) {
            bf16x4 pk = { (bf16)(st.o[df][0] * inv), (bf16)(st.o[df][1] * inv),
                          (bf16)(st.o[df][2] * inv), (bf16)(st.o[df][3] * inv) };
            *(bf16x4*)(out + (size_t)grow * DIMM + h * DHEAD + df * 16 + hi * 4) = pk;
        }
    }
}

// ---------------------------------------------------------------------------
extern "C" void kernel_launch(void* const* d_in, const int* in_sizes, int n_in,
                              void* d_out, int out_size, void* d_ws, size_t ws_size,
                              hipStream_t stream)
{
    (void)in_sizes; (void)n_in; (void)out_size;
    const float* x    = (const float*)d_in[0];
    const float* ln1g = (const float*)d_in[1];
    const float* ln1b = (const float*)d_in[2];
    const float* ln2g = (const float*)d_in[3];
    const float* ln2b = (const float*)d_in[4];
    const float* wqkv = (const float*)d_in[5];
    const float* wout = (const float*)d_in[6];
    const float* bout = (const float*)d_in[7];
    const float* wff1 = (const float*)d_in[8];
    const float* bff1 = (const float*)d_in[9];
    const float* wff2 = (const float*)d_in[10];
    const float* bff2 = (const float*)d_in[11];

    char* ws = (char*)d_ws;
    const dim3 blk(256);
    const dim3 blk512(512);
    const bool splitk = ws_size >= 92274688ULL;   // 88 MB packed layout

    if (splitk) {
        bf16*  wff2T = (bf16*)(ws);
        bf16*  woutT = (bf16*)(ws + 8388608);
        bf16*  wff1T = (bf16*)(ws + 10485760);
        bf16*  wqkvT = (bf16*)(ws + 18874368);
        bf16*  hbuf  = (bf16*)(ws + 25165824);
        bf16*  qkvb  = (bf16*)(ws + 33554432);
        bf16*  vT    = (bf16*)(ws + 58720256);
        bf16*  attnb = (bf16*)(ws + 67108864);
        float* x2    = (float*)(ws + 75497472);
        bf16*  fbuf  = (bf16*)(ws + 41943040);
        float* p0    = (float*)(ws + 8388608);
        float* p1    = (float*)(ws + 25165824);

        wcast_kernel<<<dim3(12288), blk, 0, stream>>>(
            wqkv, wqkvT, wout, woutT, wff1, wff1T, wff2, wff2T);

        ln_cast_kernel<<<NROWS, blk, 0, stream>>>(x, ln1g, ln1b, hbuf);
        gemm_bt_kernel<0><<<(NROWS / 128) * (QKV3 / 128), blk, 0, stream>>>(
            hbuf, wqkvT, nullptr, nullptr, qkvb, NROWS, QKV3, DIMM, DIMM);
        vtrans_kernel<<<dim3(SEQ / 64, BATCH * NHEAD), blk, 0, stream>>>(qkvb, vT);
        attn_kernel<<<dim3(1024), blk, 0, stream>>>(qkvb, vT, attnb);
        gemm_bt_kernel<1><<<(NROWS / 128) * (DIMM / 128), blk, 0, stream>>>(
            attnb, woutT, bout, x, x2, NROWS, DIMM, DIMM, DIMM);
        ln_cast_kernel<<<NROWS, blk, 0, stream>>>(x2, ln2g, ln2b, hbuf);
        gemm256_kernel<2><<<(NROWS / 256) * (FFD / 256), blk512, 0, stream>>>(
            hbuf, wff1T, bff1, fbuf, NROWS, FFD, DIMM, DIMM);
        gemm_bt_kernel<3><<<2 * (NROWS / 128) * (DIMM / 128), blk, 0, stream>>>(
            fbuf, wff2T, nullptr, (const float*)p1, p0, NROWS, DIMM, FFD / 2, FFD);
        ff2_reduce_kernel<<<(NROWS * DIMM) / 1024, blk, 0, stream>>>(
            p0, p1, bff2, x2, (float*)d_out);
    } else {
        bf16*  wqkvT = (bf16*)(ws);
        bf16*  woutT = (bf16*)(ws + 6291456);
        bf16*  wff1T = (bf16*)(ws + 8388608);
        bf16*  wff2T = (bf16*)(ws + 16777216);
        float* x2    = (float*)(ws + 25165824);
        bf16*  vT    = (bf16*)(ws + 25165824);
        bf16*  hbuf  = (bf16*)(ws + 41943040);
        bf16*  qkvb  = (bf16*)(ws + 50331648);
        bf16*  attnb = (bf16*)(ws + 75497472);
        bf16*  fbuf  = (bf16*)(ws + 50331648);

        wcast_kernel<<<dim3(12288), blk, 0, stream>>>(
            wqkv, wqkvT, wout, woutT, wff1, wff1T, wff2, wff2T);

        ln_cast_kernel<<<NROWS, blk, 0, stream>>>(x, ln1g, ln1b, hbuf);
        gemm_bt_kernel<0><<<(NROWS / 128) * (QKV3 / 128), blk, 0, stream>>>(
            hbuf, wqkvT, nullptr, nullptr, qkvb, NROWS, QKV3, DIMM, DIMM);
        vtrans_kernel<<<dim3(SEQ / 64, BATCH * NHEAD), blk, 0, stream>>>(qkvb, vT);
        attn_kernel<<<dim3(1024), blk, 0, stream>>>(qkvb, vT, attnb);
        gemm_bt_kernel<1><<<(NROWS / 128) * (DIMM / 128), blk, 0, stream>>>(
            attnb, woutT, bout, x, x2, NROWS, DIMM, DIMM, DIMM);
        ln_cast_kernel<<<NROWS, blk, 0, stream>>>(x2, ln2g, ln2b, hbuf);
        gemm256_kernel<2><<<(NROWS / 256) * (FFD / 256), blk512, 0, stream>>>(
            hbuf, wff1T, bff1, fbuf, NROWS, FFD, DIMM, DIMM);
        gemm_bt_kernel<1><<<(NROWS / 128) * (DIMM / 128), blk, 0, stream>>>(
            fbuf, wff2T, bff2, x2, (float*)d_out, NROWS, DIMM, FFD, FFD);
    }
}

// Round 22
// 252.678 us; speedup vs baseline: 1.0122x; 1.0083x over previous
//
#include <hip/hip_runtime.h>
#include <hip/hip_bf16.h>
#include <math.h>

#define SEQ   2048
#define BATCH 2
#define NROWS 4096      /* BATCH*SEQ */
#define DIMM  1024
#define QKV3  3072
#define FFD   4096
#define NHEAD 16
#define DHEAD 64

typedef __bf16 bf16;
typedef __bf16 bf16x4 __attribute__((ext_vector_type(4)));
typedef __bf16 bf16x8 __attribute__((ext_vector_type(8)));
typedef float  f32x4  __attribute__((ext_vector_type(4)));

static __device__ __forceinline__ f32x4 mfma16(bf16x8 a, bf16x8 b, f32x4 c) {
    return __builtin_amdgcn_mfma_f32_16x16x32_bf16(a, b, c, 0, 0, 0);
}

#define GLDS16(gp, lp) __builtin_amdgcn_global_load_lds( \
    (__attribute__((address_space(1))) void*)(gp),       \
    (__attribute__((address_space(3))) void*)(lp), 16, 0, 0)

#define MEMFENCE asm volatile("" ::: "memory")

// ---------------------------------------------------------------------------
// PREP kernel: merged weight transpose+cast (12288 tile-blocks) AND LayerNorm1
// (4096 row-blocks) in ONE launch — the two phases are fully independent
// (weights vs x; disjoint outputs), so fusing removes a serialization point.
// ---------------------------------------------------------------------------
__global__ __launch_bounds__(256) void prep_kernel(
    const float* __restrict__ wqkv, bf16* __restrict__ wqkvT,
    const float* __restrict__ wout, bf16* __restrict__ woutT,
    const float* __restrict__ wff1, bf16* __restrict__ wff1T,
    const float* __restrict__ wff2, bf16* __restrict__ wff2T,
    const float* __restrict__ x, const float* __restrict__ g,
    const float* __restrict__ bb, bf16* __restrict__ lnout)
{
    __shared__ float tile[32][33];
    __shared__ float ss[4], ssq[4];
    int t = blockIdx.x;

    if (t >= 12288) {
        // ---- LayerNorm row (t - 12288) ----
        const int row = t - 12288;
        const int tt = threadIdx.x;
        const float4 v = ((const float4*)(x + (size_t)row * DIMM))[tt];
        float s  = v.x + v.y + v.z + v.w;
        float sq = v.x * v.x + v.y * v.y + v.z * v.z + v.w * v.w;
        #pragma unroll
        for (int m = 1; m < 64; m <<= 1) {
            s  += __shfl_xor(s, m, 64);
            sq += __shfl_xor(sq, m, 64);
        }
        const int wave = tt >> 6;
        if ((tt & 63) == 0) { ss[wave] = s; ssq[wave] = sq; }
        __syncthreads();
        s  = ss[0] + ss[1] + ss[2] + ss[3];
        sq = ssq[0] + ssq[1] + ssq[2] + ssq[3];
        const float mean = s * (1.0f / DIMM);
        const float var  = sq * (1.0f / DIMM) - mean * mean;
        const float rs   = rsqrtf(var + 1e-5f);
        const float4 gv = ((const float4*)g)[tt];
        const float4 bv = ((const float4*)bb)[tt];
        bf16* o = lnout + (size_t)row * DIMM + tt * 4;
        o[0] = (bf16)((v.x - mean) * rs * gv.x + bv.x);
        o[1] = (bf16)((v.y - mean) * rs * gv.y + bv.y);
        o[2] = (bf16)((v.z - mean) * rs * gv.z + bv.z);
        o[3] = (bf16)((v.w - mean) * rs * gv.w + bv.w);
        return;
    }

    // ---- weight transpose+cast tile ----
    const float* src; bf16* dst; int K, N, nx;
    if (t < 3072)      { src = wqkv; dst = wqkvT; K = DIMM; N = QKV3; nx = 96;  }
    else if (t < 4096) { src = wout; dst = woutT; K = DIMM; N = DIMM; nx = 32; t -= 3072; }
    else if (t < 8192) { src = wff1; dst = wff1T; K = DIMM; N = FFD;  nx = 128; t -= 4096; }
    else               { src = wff2; dst = wff2T; K = FFD;  N = DIMM; nx = 32; t -= 8192; }
    const int k0 = (t / nx) * 32;
    const int n0 = (t - (t / nx) * nx) * 32;

    const int r = threadIdx.x >> 5;   // 0..7
    const int c = threadIdx.x & 31;
    #pragma unroll
    for (int i = 0; i < 4; ++i)
        tile[r + 8 * i][c] = src[(size_t)(k0 + r + 8 * i) * N + n0 + c];
    __syncthreads();
    #pragma unroll
    for (int i = 0; i < 4; ++i)
        dst[(size_t)(n0 + r + 8 * i) * K + k0 + c] = (bf16)tile[c][r + 8 * i];
}

// ---------------------------------------------------------------------------
// LayerNorm fp32 [NROWS][1024] -> bf16, one block per row (used for LN2)
// ---------------------------------------------------------------------------
__global__ __launch_bounds__(256) void ln_cast_kernel(
    const float* __restrict__ x, const float* __restrict__ g,
    const float* __restrict__ b, bf16* __restrict__ out)
{
    const int row = blockIdx.x;
    const int t = threadIdx.x;
    const float4 v = ((const float4*)(x + (size_t)row * DIMM))[t];
    float s  = v.x + v.y + v.z + v.w;
    float sq = v.x * v.x + v.y * v.y + v.z * v.z + v.w * v.w;
    #pragma unroll
    for (int m = 1; m < 64; m <<= 1) {
        s  += __shfl_xor(s, m, 64);
        sq += __shfl_xor(sq, m, 64);
    }
    __shared__ float ss[4], ssq[4];
    const int wave = t >> 6;
    if ((t & 63) == 0) { ss[wave] = s; ssq[wave] = sq; }
    __syncthreads();
    s  = ss[0] + ss[1] + ss[2] + ss[3];
    sq = ssq[0] + ssq[1] + ssq[2] + ssq[3];
    const float mean = s * (1.0f / DIMM);
    const float var  = sq * (1.0f / DIMM) - mean * mean;
    const float rs   = rsqrtf(var + 1e-5f);
    const float4 gv = ((const float4*)g)[t];
    const float4 bv = ((const float4*)b)[t];
    bf16* o = out + (size_t)row * DIMM + t * 4;
    o[0] = (bf16)((v.x - mean) * rs * gv.x + bv.x);
    o[1] = (bf16)((v.y - mean) * rs * gv.y + bv.y);
    o[2] = (bf16)((v.z - mean) * rs * gv.z + bv.z);
    o[3] = (bf16)((v.w - mean) * rs * gv.w + bv.w);
}

// ---------------------------------------------------------------------------
// 256x256 8-wave GEMM — 4-phase fine-interleaved schedule (r13/r14 proven).
// Used for FF1 only (grid 256 = exactly 1 block/CU).
// EPI: 2 = +bias, GELU, bf16 out
// ---------------------------------------------------------------------------
template<int EPI>
__global__ __launch_bounds__(512, 2)
void gemm256_kernel(const bf16* __restrict__ A, const bf16* __restrict__ BT,
                    const float* __restrict__ bias, bf16* __restrict__ C,
                    int M, int N, int K, int ld)
{
    __shared__ bf16 As_[2][2][8192];   // [dbuf][half][128 rows x 64 k]
    __shared__ bf16 Bs_[2][2][8192];
    const int nb = N >> 8;
    const int chunk = (int)gridDim.x >> 3;
    const int idx = ((int)blockIdx.x & 7) * chunk + ((int)blockIdx.x >> 3);
    const int bm = idx / nb, bn = idx - bm * nb;
    const int tm = bm << 8, tn = bn << 8;
    const int tid = threadIdx.x;
    const int lane = tid & 63, w = tid >> 6;   // 8 waves
    const int wr = w >> 2, wc = w & 3;
    const int lq = lane & 15, hk = lane >> 4;

    const int sr  = lane >> 3;
    const int sgo = (((lane & 7) ^ sr) << 3);
    const bf16* gA0 = A  + (size_t)(tm +       w * 8 + sr) * ld + sgo;
    const bf16* gA1 = A  + (size_t)(tm + 128 + w * 8 + sr) * ld + sgo;
    const bf16* gB0 = BT + (size_t)(tn +       w * 8 + sr) * ld + sgo;
    const bf16* gB1 = BT + (size_t)(tn + 128 + w * 8 + sr) * ld + sgo;
    const size_t l64 = (size_t)64 * ld;

#define STG_A0(D, T) do { const size_t ko_ = (size_t)(T) * 64;              \
        GLDS16(gA0 + ko_,       &As_[D][0][w * 512]);                       \
        GLDS16(gA0 + ko_ + l64, &As_[D][0][4096 + w * 512]); } while (0)
#define STG_A1(D, T) do { const size_t ko_ = (size_t)(T) * 64;              \
        GLDS16(gA1 + ko_,       &As_[D][1][w * 512]);                       \
        GLDS16(gA1 + ko_ + l64, &As_[D][1][4096 + w * 512]); } while (0)
#define STG_B0(D, T) do { const size_t ko_ = (size_t)(T) * 64;              \
        GLDS16(gB0 + ko_,       &Bs_[D][0][w * 512]);                       \
        GLDS16(gB0 + ko_ + l64, &Bs_[D][0][4096 + w * 512]); } while (0)
#define STG_B1(D, T) do { const size_t ko_ = (size_t)(T) * 64;              \
        GLDS16(gB1 + ko_,       &Bs_[D][1][w * 512]);                       \
        GLDS16(gB1 + ko_ + l64, &Bs_[D][1][4096 + w * 512]); } while (0)

    f32x4 acc[8][4] = {};
    const int NT = K >> 6;

    STG_A0(0, 0); STG_B1(0, 0); STG_B0(0, 0); STG_A1(0, 0);
    STG_B0(1, 1); STG_A1(1, 1);

    for (int t = 0; t < NT; ++t) {
        const int d = t & 1, e = d ^ 1;
        if (t == NT - 1) asm volatile("s_waitcnt vmcnt(0)" ::: "memory");
        else             asm volatile("s_waitcnt vmcnt(4)" ::: "memory");
        __builtin_amdgcn_s_barrier();
        MEMFENCE;

        const char* Ah0 = (const char*)&As_[d][0][0];
        const char* Ah1 = (const char*)&As_[d][1][0];
        const char* Bh0 = (const char*)&Bs_[d][0][0];
        const char* Bh1 = (const char*)&Bs_[d][1][0];
        bf16x8 af[4][2], bfv[2][2];

#define DO_MFMA(MH, NH) do {                                                 \
        __builtin_amdgcn_s_setprio(1);                                       \
        _Pragma("unroll")                                                    \
        for (int mi = 0; mi < 4; ++mi)                                       \
            _Pragma("unroll")                                                \
            for (int nj = 0; nj < 2; ++nj)                                   \
                _Pragma("unroll")                                            \
                for (int kk = 0; kk < 2; ++kk)                               \
                    acc[(MH)*4+mi][(NH)*2+nj] =                              \
                        mfma16(bfv[nj][kk], af[mi][kk], acc[(MH)*4+mi][(NH)*2+nj]); \
        __builtin_amdgcn_s_setprio(0); } while (0)

        {   // ph1 (0,0)
            #pragma unroll
            for (int mi = 0; mi < 4; ++mi) {
                const int lr = wr * 64 + mi * 16 + lq;
                af[mi][0] = *(const bf16x8*)(Ah0 + lr * 128 + ((hk ^ (lr & 7)) << 4));
                af[mi][1] = *(const bf16x8*)(Ah0 + lr * 128 + (((4 + hk) ^ (lr & 7)) << 4));
            }
            #pragma unroll
            for (int nj = 0; nj < 2; ++nj) {
                const int lc = wc * 32 + nj * 16 + lq;
                bfv[nj][0] = *(const bf16x8*)(Bh0 + lc * 128 + ((hk ^ (lc & 7)) << 4));
                bfv[nj][1] = *(const bf16x8*)(Bh0 + lc * 128 + (((4 + hk) ^ (lc & 7)) << 4));
            }
            if (t + 1 < NT) STG_A0(e, t + 1);
            DO_MFMA(0, 0);
        }
        MEMFENCE; __builtin_amdgcn_s_barrier(); MEMFENCE;
        {   // ph2 (1,0)
            #pragma unroll
            for (int mi = 0; mi < 4; ++mi) {
                const int lr = wr * 64 + mi * 16 + lq;
                af[mi][0] = *(const bf16x8*)(Ah1 + lr * 128 + ((hk ^ (lr & 7)) << 4));
                af[mi][1] = *(const bf16x8*)(Ah1 + lr * 128 + (((4 + hk) ^ (lr & 7)) << 4));
            }
            if (t + 1 < NT) STG_B1(e, t + 1);
            DO_MFMA(1, 0);
        }
        MEMFENCE; __builtin_amdgcn_s_barrier(); MEMFENCE;
        {   // ph3 (1,1)
            #pragma unroll
            for (int nj = 0; nj < 2; ++nj) {
                const int lc = wc * 32 + nj * 16 + lq;
                bfv[nj][0] = *(const bf16x8*)(Bh1 + lc * 128 + ((hk ^ (lc & 7)) << 4));
                bfv[nj][1] = *(const bf16x8*)(Bh1 + lc * 128 + (((4 + hk) ^ (lc & 7)) << 4));
            }
            if (t + 2 < NT) STG_B0(d, t + 2);
            DO_MFMA(1, 1);
        }
        MEMFENCE; __builtin_amdgcn_s_barrier(); MEMFENCE;
        {   // ph4 (0,1)
            #pragma unroll
            for (int mi = 0; mi < 4; ++mi) {
                const int lr = wr * 64 + mi * 16 + lq;
                af[mi][0] = *(const bf16x8*)(Ah0 + lr * 128 + ((hk ^ (lr & 7)) << 4));
                af[mi][1] = *(const bf16x8*)(Ah0 + lr * 128 + (((4 + hk) ^ (lr & 7)) << 4));
            }
            if (t + 2 < NT) STG_A1(d, t + 2);
            DO_MFMA(0, 1);
        }
        MEMFENCE; __builtin_amdgcn_s_barrier(); MEMFENCE;
#undef DO_MFMA
    }
#undef STG_A0
#undef STG_A1
#undef STG_B0
#undef STG_B1

    #pragma unroll
    for (int i = 0; i < 8; ++i) {
        const int mh = i >> 2, mi = i & 3;
        const int row = tm + mh * 128 + wr * 64 + mi * 16 + lq;
        #pragma unroll
        for (int j = 0; j < 4; ++j) {
            const int nh = j >> 1, nj = j & 1;
            const int col = tn + nh * 128 + wc * 32 + nj * 16 + (hk << 2);
            if (EPI == 0) {
                bf16x4 pk = { (bf16)acc[i][j][0], (bf16)acc[i][j][1],
                              (bf16)acc[i][j][2], (bf16)acc[i][j][3] };
                *(bf16x4*)(C + (size_t)row * N + col) = pk;
            } else {
                const float4 bv4 = *(const float4*)(bias + col);
                float v0 = acc[i][j][0] + bv4.x, v1 = acc[i][j][1] + bv4.y;
                float v2 = acc[i][j][2] + bv4.z, v3 = acc[i][j][3] + bv4.w;
                bf16x4 pk = {
                    (bf16)(0.5f * v0 * (1.0f + erff(v0 * 0.70710678118654752f))),
                    (bf16)(0.5f * v1 * (1.0f + erff(v1 * 0.70710678118654752f))),
                    (bf16)(0.5f * v2 * (1.0f + erff(v2 * 0.70710678118654752f))),
                    (bf16)(0.5f * v3 * (1.0f + erff(v3 * 0.70710678118654752f))) };
                *(bf16x4*)(C + (size_t)row * N + col) = pk;
            }
        }
    }
}

// ---------------------------------------------------------------------------
// 128x128 3-stage counted-vmcnt GEMM + swapped-operand vectorized epilogue.
// Used for QKV (768 blk, 3/CU), out-proj, FF2 split-K.
// EPI: 0 = bf16 out; 1 = +bias +residual, fp32 out; 3 = split-K partial
// ---------------------------------------------------------------------------
template<int EPI>
__global__ __launch_bounds__(256, 3)
void gemm_bt_kernel(const bf16* __restrict__ A, const bf16* __restrict__ BT,
                    const float* __restrict__ bias, const float* __restrict__ res,
                    void* __restrict__ Cout, int M, int N, int K, int ld)
{
    __shared__ bf16 As[3][4096];   // [buf][128 m][32 k]
    __shared__ bf16 Bs[3][4096];
    const int nb = N >> 7;
    const int chunk = (int)gridDim.x >> 3;
    int idx = (blockIdx.x & 7) * chunk + (blockIdx.x >> 3);
    int ks = 0;
    if (EPI == 3) {
        const int tiles = (M >> 7) * nb;
        ks = idx / tiles;
        idx -= ks * tiles;
    }
    const int bm = idx / nb, bn = idx - bm * nb;
    const int tm = bm << 7, tn = bn << 7;
    const int tid = threadIdx.x;
    const int lane = tid & 63, wave = tid >> 6;
    const int wm = (wave >> 1) << 6, wn = (wave & 1) << 6;
    const int kofs = ks * K;

    const bf16* ga = A  + (size_t)(tm + wave * 32 + (lane >> 2)) * ld + kofs + ((lane & 3) << 3);
    const bf16* gb = BT + (size_t)(tn + wave * 32 + (lane >> 2)) * ld + kofs + ((lane & 3) << 3);
    const size_t k16 = (size_t)16 * ld;

    f32x4 acc[4][4] = {};
    const int ro = (lane & 15) * 32 + ((lane >> 4) << 3);

#define GSTAGE(BUF, KO) do {                          \
        bf16* la_ = &As[BUF][wave * 1024];            \
        bf16* lb_ = &Bs[BUF][wave * 1024];            \
        GLDS16(ga + (KO),       la_);                 \
        GLDS16(ga + (KO) + k16, la_ + 512);           \
        GLDS16(gb + (KO),       lb_);                 \
        GLDS16(gb + (KO) + k16, lb_ + 512);           \
    } while (0)

    GSTAGE(0, 0);
    GSTAGE(1, 32);
    GSTAGE(2, 64);
    int cur = 0;
    for (int k0 = 0; k0 < K; k0 += 32) {
        if (k0 + 96 <= K)      asm volatile("s_waitcnt vmcnt(8)" ::: "memory");
        else if (k0 + 64 <= K) asm volatile("s_waitcnt vmcnt(4)" ::: "memory");
        else                   asm volatile("s_waitcnt vmcnt(0)" ::: "memory");
        __builtin_amdgcn_s_barrier();

        bf16x8 af[4], bfr[4];
        #pragma unroll
        for (int i = 0; i < 4; ++i) {
            af[i]  = *(const bf16x8*)(&As[cur][0] + (wm + i * 16) * 32 + ro);
            bfr[i] = *(const bf16x8*)(&Bs[cur][0] + (wn + i * 16) * 32 + ro);
        }
        #pragma unroll
        for (int i = 0; i < 4; ++i)
            #pragma unroll
            for (int j = 0; j < 4; ++j)
                acc[i][j] = mfma16(bfr[j], af[i], acc[i][j]);   // swapped

        MEMFENCE;
        __builtin_amdgcn_s_barrier();
        MEMFENCE;
        if (k0 + 96 < K) GSTAGE(cur, k0 + 96);
        cur = (cur == 2) ? 0 : cur + 1;
    }
#undef GSTAGE

    // swapped layout: acc[i][j][r] = C[tm+wm+i*16+lq][tn+wn+j*16+hk*4+r]
    const int lq = lane & 15, hk = lane >> 4;
    const int r0 = tm + wm + lq;
    const int c0 = tn + wn + (hk << 2);
    if (EPI == 0) {
        bf16* C = (bf16*)Cout;
        #pragma unroll
        for (int j = 0; j < 4; ++j)
            #pragma unroll
            for (int i = 0; i < 4; ++i) {
                bf16x4 pk = { (bf16)acc[i][j][0], (bf16)acc[i][j][1],
                              (bf16)acc[i][j][2], (bf16)acc[i][j][3] };
                *(bf16x4*)(C + (size_t)(r0 + i * 16) * N + c0 + j * 16) = pk;
            }
    } else if (EPI == 1) {
        float* C = (float*)Cout;
        #pragma unroll
        for (int j = 0; j < 4; ++j) {
            const float4 bv4 = *(const float4*)(bias + c0 + j * 16);
            #pragma unroll
            for (int i = 0; i < 4; ++i) {
                const size_t off = (size_t)(r0 + i * 16) * N + c0 + j * 16;
                const float4 rv = *(const float4*)(res + off);
                float4 o;
                o.x = acc[i][j][0] + bv4.x + rv.x;
                o.y = acc[i][j][1] + bv4.y + rv.y;
                o.z = acc[i][j][2] + bv4.z + rv.z;
                o.w = acc[i][j][3] + bv4.w + rv.w;
                *(float4*)(C + off) = o;
            }
        }
    } else {
        float* C = (float*)(ks == 0 ? Cout : (void*)res);
        #pragma unroll
        for (int j = 0; j < 4; ++j)
            #pragma unroll
            for (int i = 0; i < 4; ++i) {
                float4 o = { acc[i][j][0], acc[i][j][1], acc[i][j][2], acc[i][j][3] };
                *(float4*)(C + (size_t)(r0 + i * 16) * N + c0 + j * 16) = o;
            }
    }
}

// ---------------------------------------------------------------------------
// FF2 split-K reduce: out = p0 + p1 + bias + res  (all fp32, [NROWS][DIMM])
// ---------------------------------------------------------------------------
__global__ __launch_bounds__(256) void ff2_reduce_kernel(
    const float* __restrict__ p0, const float* __restrict__ p1,
    const float* __restrict__ bias, const float* __restrict__ res,
    float* __restrict__ out)
{
    const int i = blockIdx.x * 256 + threadIdx.x;    // float4 index
    const float4 a = ((const float4*)p0)[i];
    const float4 b = ((const float4*)p1)[i];
    const float4 r = ((const float4*)res)[i];
    const float4 g = ((const float4*)bias)[i & 255];
    float4 o;
    o.x = a.x + b.x + r.x + g.x;
    o.y = a.y + b.y + r.y + g.y;
    o.z = a.z + b.z + r.z + g.z;
    o.w = a.w + b.w + r.w + g.w;
    ((float4*)out)[i] = o;
}

// ---------------------------------------------------------------------------
// V transpose per head, PERMUTED columns (r18 proven): within each 32-column
// block, position n' holds V column n with
//   n' = (n&3) | ((n>>4)&1)<<2 | ((n>>2)&3)<<3
// ---------------------------------------------------------------------------
__global__ __launch_bounds__(256) void vtrans_kernel(
    const bf16* __restrict__ qkv, bf16* __restrict__ vT)
{
    __shared__ bf16 t[64 * 64];
    const int n0 = blockIdx.x * 64;
    const int bh = blockIdx.y;
    const int b = bh >> 4, h = bh & 15;
    const bf16* src = qkv + (size_t)(b * SEQ + n0) * QKV3 + 2 * DIMM + h * DHEAD;

    #pragma unroll
    for (int it = 0; it < 2; ++it) {
        const int c = it * 256 + threadIdx.x;
        const int n = c >> 3, d8 = (c & 7) * 8;
        const bf16x8 v8 = *(const bf16x8*)(src + (size_t)n * QKV3 + d8);
        const int byte = (n * 128 + d8 * 2) ^ (((n >> 3) & 7) << 4);
        *(bf16x8*)((char*)t + byte) = v8;
    }
    __syncthreads();
    #pragma unroll
    for (int it = 0; it < 2; ++it) {
        const int c = it * 256 + threadIdx.x;
        const int d = c >> 3, nc = c & 7;
        bf16x8 o8;
        #pragma unroll
        for (int i = 0; i < 8; ++i) {
            const int n = nc * 8 + i;
            const int byte = (n * 128 + d * 2) ^ ((nc & 7) << 4);
            o8[i] = *(const bf16*)((const char*)t + byte);
        }
        bf16* dstrow = vT + (size_t)bh * DHEAD * SEQ + (size_t)d * SEQ;
        #pragma unroll
        for (int half = 0; half < 2; ++half) {
            const int nb2 = nc * 8 + half * 4;
            const int nabs = n0 + nb2;
            const int off = nb2 & 31;
            const int offp = (((off >> 4) & 1) << 2) | (((off >> 2) & 3) << 3);
            bf16x4 q4 = { o8[half * 4 + 0], o8[half * 4 + 1],
                          o8[half * 4 + 2], o8[half * 4 + 3] };
            *(bf16x4*)(dstrow + (nabs & ~31) + offp) = q4;
        }
    }
}

// ---------------------------------------------------------------------------
// Flash attention v8 (r19/r21-proven, 61 us best): P-in-register PV with
// permuted vT', 2x unrolled K-loop (compile-time buffer indices), lane-local
// l with epilogue reduction.
// ---------------------------------------------------------------------------
struct AttnState { float m, l; f32x4 o[4]; };

static __device__ __forceinline__ void attn_body(
    const bf16* __restrict__ Kbuf, const bf16* __restrict__ Vbuf,
    const bf16x8* __restrict__ qf, int q, int hi, AttnState& st)
{
    // S^T = K Q^T : sv[kf][r] = S[kv=kf*16+hi*4+r][q]
    f32x4 sv[4];
    __builtin_amdgcn_s_setprio(1);
    #pragma unroll
    for (int kf = 0; kf < 4; ++kf) {
        f32x4 z = {0.f, 0.f, 0.f, 0.f};
        sv[kf] = z;
        #pragma unroll
        for (int ks = 0; ks < 2; ++ks) {
            const int row = kf * 16 + q;
            const int bo = (row * 128 + ks * 64 + (hi << 4)) ^ ((row & 7) << 4);
            const bf16x8 kfrag = *(const bf16x8*)((const char*)Kbuf + bo);
            sv[kf] = mfma16(kfrag, qf[ks], sv[kf]);
        }
    }
    __builtin_amdgcn_s_setprio(0);

    float pmax;
    {
        float a = fmaxf(fmaxf(sv[0][0], sv[0][1]), fmaxf(sv[0][2], sv[0][3]));
        float b2 = fmaxf(fmaxf(sv[1][0], sv[1][1]), fmaxf(sv[1][2], sv[1][3]));
        float c = fmaxf(fmaxf(sv[2][0], sv[2][1]), fmaxf(sv[2][2], sv[2][3]));
        float d = fmaxf(fmaxf(sv[3][0], sv[3][1]), fmaxf(sv[3][2], sv[3][3]));
        pmax = fmaxf(fmaxf(a, b2), fmaxf(c, d));
    }
    pmax = fmaxf(pmax, __shfl_xor(pmax, 16, 64));
    pmax = fmaxf(pmax, __shfl_xor(pmax, 32, 64));

    if (__any(pmax - st.m > 8.0f)) {
        const float nm = fmaxf(st.m, pmax);
        const float fr = __expf(st.m - nm);
        st.l *= fr;
        #pragma unroll
        for (int df = 0; df < 4; ++df) {
            st.o[df][0] *= fr; st.o[df][1] *= fr;
            st.o[df][2] *= fr; st.o[df][3] *= fr;
        }
        st.m = nm;
    }

    // P = exp(S - m), lane-local l accumulation (reduced in epilogue)
    float pv[4][4];
    float rsum = 0.0f;
    #pragma unroll
    for (int kf = 0; kf < 4; ++kf)
        #pragma unroll
        for (int r = 0; r < 4; ++r) {
            pv[kf][r] = __expf(sv[kf][r] - st.m);
            rsum += pv[kf][r];
        }
    st.l += rsum;

    // pack P into PV B-operands (permuted-k)
    bf16x8 pb[2];
    #pragma unroll
    for (int ks = 0; ks < 2; ++ks)
        #pragma unroll
        for (int r = 0; r < 4; ++r) {
            pb[ks][r]     = (bf16)pv[2 * ks][r];
            pb[ks][r + 4] = (bf16)pv[2 * ks + 1][r];
        }

    // O^T += V^T P^T : conflict-free b128 A-read (permutation baked in vT')
    __builtin_amdgcn_s_setprio(1);
    #pragma unroll
    for (int df = 0; df < 4; ++df) {
        const int rowv = df * 16 + q;
        #pragma unroll
        for (int ks = 0; ks < 2; ++ks) {
            const int bo = (rowv * 128 + ks * 64 + (hi << 4)) ^ ((rowv & 7) << 4);
            const bf16x8 vfrag = *(const bf16x8*)((const char*)Vbuf + bo);
            st.o[df] = mfma16(vfrag, pb[ks], st.o[df]);
        }
    }
    __builtin_amdgcn_s_setprio(0);
}

__global__ __launch_bounds__(256, 4)
void attn_kernel(const bf16* __restrict__ qkv, const bf16* __restrict__ vT,
                 bf16* __restrict__ out)
{
    __shared__ bf16 Ks[2][64 * 64];
    __shared__ bf16 Vs[2][64 * 64];
    const int bid = blockIdx.x;
    const int idx = (bid & 7) * 128 + (bid >> 3);
    const int qt = idx & 31;
    const int bh = idx >> 5;
    const int b = bh >> 4, h = bh & 15;
    const int tid = threadIdx.x;
    const int lane = tid & 63, wave = tid >> 6;
    const int q = lane & 15, hi = lane >> 4;

    const bf16* qbase = qkv + (size_t)(b * SEQ) * QKV3 + h * DHEAD;
    const bf16* kbase = qbase + DIMM;
    const bf16* vbase = vT + (size_t)bh * DHEAD * SEQ;

    const int q0 = qt * 64 + wave * 16;
    bf16x8 qf[2];
    {
        const bf16* qp = qbase + (size_t)(q0 + q) * QKV3 + (hi << 3);
        qf[0] = *(const bf16x8*)qp;
        qf[1] = *(const bf16x8*)(qp + 32);
        #pragma unroll
        for (int j = 0; j < 8; ++j) {
            qf[0][j] = (bf16)((float)qf[0][j] * 0.125f);
            qf[1][j] = (bf16)((float)qf[1][j] * 0.125f);
        }
    }

    const int srow = lane >> 3;
    const int scol = ((lane & 7) ^ srow) << 3;
    const bf16* gk = kbase + (size_t)(wave * 16 + srow) * QKV3 + scol;
    const bf16* gv = vbase + (size_t)(wave * 16 + srow) * SEQ + scol;

#define STAGE(BUF, KT) do {                                        \
        bf16* lk_ = &Ks[BUF][wave * 1024];                         \
        bf16* lv_ = &Vs[BUF][wave * 1024];                         \
        GLDS16(gk + (size_t)(KT) * QKV3,       lk_);               \
        GLDS16(gk + (size_t)((KT) + 8) * QKV3, lk_ + 512);         \
        GLDS16(gv + (KT),                      lv_);               \
        GLDS16(gv + (KT) + 8 * SEQ,            lv_ + 512);         \
    } while (0)

    AttnState st;
    st.m = -1e30f; st.l = 0.0f;
    #pragma unroll
    for (int df = 0; df < 4; ++df) {
        f32x4 z = {0.f, 0.f, 0.f, 0.f};
        st.o[df] = z;
    }

    STAGE(0, 0);
    for (int kt = 0; kt < SEQ; kt += 128) {
        __syncthreads();                       // drains: STAGE(kt) resident
        STAGE(1, kt + 64);                     // always in range (kt+64 <= SEQ-64)
        attn_body(&Ks[0][0], &Vs[0][0], qf, q, hi, st);
        __syncthreads();                       // drains: STAGE(kt+64) resident
        if (kt + 128 < SEQ) STAGE(0, kt + 128);
        attn_body(&Ks[1][0], &Vs[1][0], qf, q, hi, st);
    }
#undef STAGE

    {
        float lt = st.l;
        lt += __shfl_xor(lt, 16, 64);
        lt += __shfl_xor(lt, 32, 64);
        const float inv = 1.0f / lt;
        const int grow = b * SEQ + q0 + q;
        #pragma unroll
        for (int df = 0; df < 4; ++df) {
            bf16x4 pk = { (bf16)(st.o[df][0] * inv), (bf16)(st.o[df][1] * inv),
                          (bf16)(st.o[df][2] * inv), (bf16)(st.o[df][3] * inv) };
            *(bf16x4*)(out + (size_t)grow * DIMM + h * DHEAD + df * 16 + hi * 4) = pk;
        }
    }
}

// ---------------------------------------------------------------------------
extern "C" void kernel_launch(void* const* d_in, const int* in_sizes, int n_in,
                              void* d_out, int out_size, void* d_ws, size_t ws_size,
                              hipStream_t stream)
{
    (void)in_sizes; (void)n_in; (void)out_size;
    const float* x    = (const float*)d_in[0];
    const float* ln1g = (const float*)d_in[1];
    const float* ln1b = (const float*)d_in[2];
    const float* ln2g = (const float*)d_in[3];
    const float* ln2b = (const float*)d_in[4];
    const float* wqkv = (const float*)d_in[5];
    const float* wout = (const float*)d_in[6];
    const float* bout = (const float*)d_in[7];
    const float* wff1 = (const float*)d_in[8];
    const float* bff1 = (const float*)d_in[9];
    const float* wff2 = (const float*)d_in[10];
    const float* bff2 = (const float*)d_in[11];

    char* ws = (char*)d_ws;
    const dim3 blk(256);
    const dim3 blk512(512);
    const bool splitk = ws_size >= 92274688ULL;   // 88 MB packed layout

    if (splitk) {
        bf16*  wff2T = (bf16*)(ws);
        bf16*  woutT = (bf16*)(ws + 8388608);
        bf16*  wff1T = (bf16*)(ws + 10485760);
        bf16*  wqkvT = (bf16*)(ws + 18874368);
        bf16*  hbuf  = (bf16*)(ws + 25165824);
        bf16*  qkvb  = (bf16*)(ws + 33554432);
        bf16*  vT    = (bf16*)(ws + 58720256);
        bf16*  attnb = (bf16*)(ws + 67108864);
        float* x2    = (float*)(ws + 75497472);
        bf16*  fbuf  = (bf16*)(ws + 41943040);
        float* p0    = (float*)(ws + 8388608);
        float* p1    = (float*)(ws + 25165824);

        prep_kernel<<<dim3(16384), blk, 0, stream>>>(
            wqkv, wqkvT, wout, woutT, wff1, wff1T, wff2, wff2T,
            x, ln1g, ln1b, hbuf);
        gemm_bt_kernel<0><<<(NROWS / 128) * (QKV3 / 128), blk, 0, stream>>>(
            hbuf, wqkvT, nullptr, nullptr, qkvb, NROWS, QKV3, DIMM, DIMM);
        vtrans_kernel<<<dim3(SEQ / 64, BATCH * NHEAD), blk, 0, stream>>>(qkvb, vT);
        attn_kernel<<<dim3(1024), blk, 0, stream>>>(qkvb, vT, attnb);
        gemm_bt_kernel<1><<<(NROWS / 128) * (DIMM / 128), blk, 0, stream>>>(
            attnb, woutT, bout, x, x2, NROWS, DIMM, DIMM, DIMM);
        ln_cast_kernel<<<NROWS, blk, 0, stream>>>(x2, ln2g, ln2b, hbuf);
        gemm256_kernel<2><<<(NROWS / 256) * (FFD / 256), blk512, 0, stream>>>(
            hbuf, wff1T, bff1, fbuf, NROWS, FFD, DIMM, DIMM);
        gemm_bt_kernel<3><<<2 * (NROWS / 128) * (DIMM / 128), blk, 0, stream>>>(
            fbuf, wff2T, nullptr, (const float*)p1, p0, NROWS, DIMM, FFD / 2, FFD);
        ff2_reduce_kernel<<<(NROWS * DIMM) / 1024, blk, 0, stream>>>(
            p0, p1, bff2, x2, (float*)d_out);
    } else {
        bf16*  wqkvT = (bf16*)(ws);
        bf16*  woutT = (bf16*)(ws + 6291456);
        bf16*  wff1T = (bf16*)(ws + 8388608);
        bf16*  wff2T = (bf16*)(ws + 16777216);
        float* x2    = (float*)(ws + 25165824);
        bf16*  vT    = (bf16*)(ws + 25165824);
        bf16*  hbuf  = (bf16*)(ws + 41943040);
        bf16*  qkvb  = (bf16*)(ws + 50331648);
        bf16*  attnb = (bf16*)(ws + 75497472);
        bf16*  fbuf  = (bf16*)(ws + 50331648);

        prep_kernel<<<dim3(16384), blk, 0, stream>>>(
            wqkv, wqkvT, wout, woutT, wff1, wff1T, wff2, wff2T,
            x, ln1g, ln1b, hbuf);
        gemm_bt_kernel<0><<<(NROWS / 128) * (QKV3 / 128), blk, 0, stream>>>(
            hbuf, wqkvT, nullptr, nullptr, qkvb, NROWS, QKV3, DIMM, DIMM);
        vtrans_kernel<<<dim3(SEQ / 64, BATCH * NHEAD), blk, 0, stream>>>(qkvb, vT);
        attn_kernel<<<dim3(1024), blk, 0, stream>>>(qkvb, vT, attnb);
        gemm_bt_kernel<1><<<(NROWS / 128) * (DIMM / 128), blk, 0, stream>>>(
            attnb, woutT, bout, x, x2, NROWS, DIMM, DIMM, DIMM);
        ln_cast_kernel<<<NROWS, blk, 0, stream>>>(x2, ln2g, ln2b, hbuf);
        gemm256_kernel<2><<<(NROWS / 256) * (FFD / 256), blk512, 0, stream>>>(
            hbuf, wff1T, bff1, fbuf, NROWS, FFD, DIMM, DIMM);
        gemm_bt_kernel<1><<<(NROWS / 128) * (DIMM / 128), blk, 0, stream>>>(
            fbuf, wff2T, bff2, x2, (float*)d_out, NROWS, DIMM, FFD, FFD);
    }
}

// Round 23
// 250.688 us; speedup vs baseline: 1.0203x; 1.0079x over previous
//
#include <hip/hip_runtime.h>
#include <hip/hip_bf16.h>
#include <math.h>

#define SEQ   2048
#define BATCH 2
#define NROWS 4096      /* BATCH*SEQ */
#define DIMM  1024
#define QKV3  3072
#define FFD   4096
#define NHEAD 16
#define DHEAD 64

typedef __bf16 bf16;
typedef __bf16 bf16x4 __attribute__((ext_vector_type(4)));
typedef __bf16 bf16x8 __attribute__((ext_vector_type(8)));
typedef float  f32x4  __attribute__((ext_vector_type(4)));

static __device__ __forceinline__ f32x4 mfma16(bf16x8 a, bf16x8 b, f32x4 c) {
    return __builtin_amdgcn_mfma_f32_16x16x32_bf16(a, b, c, 0, 0, 0);
}

#define GLDS16(gp, lp) __builtin_amdgcn_global_load_lds( \
    (__attribute__((address_space(1))) void*)(gp),       \
    (__attribute__((address_space(3))) void*)(lp), 16, 0, 0)

#define MEMFENCE asm volatile("" ::: "memory")

// ---------------------------------------------------------------------------
// PREP kernel: merged weight transpose+cast (12288 tile-blocks) AND LayerNorm1
// (4096 row-blocks) in ONE launch (r22 proven).
// ---------------------------------------------------------------------------
__global__ __launch_bounds__(256) void prep_kernel(
    const float* __restrict__ wqkv, bf16* __restrict__ wqkvT,
    const float* __restrict__ wout, bf16* __restrict__ woutT,
    const float* __restrict__ wff1, bf16* __restrict__ wff1T,
    const float* __restrict__ wff2, bf16* __restrict__ wff2T,
    const float* __restrict__ x, const float* __restrict__ g,
    const float* __restrict__ bb, bf16* __restrict__ lnout)
{
    __shared__ float tile[32][33];
    __shared__ float ss[4], ssq[4];
    int t = blockIdx.x;

    if (t >= 12288) {
        // ---- LayerNorm row (t - 12288) ----
        const int row = t - 12288;
        const int tt = threadIdx.x;
        const float4 v = ((const float4*)(x + (size_t)row * DIMM))[tt];
        float s  = v.x + v.y + v.z + v.w;
        float sq = v.x * v.x + v.y * v.y + v.z * v.z + v.w * v.w;
        #pragma unroll
        for (int m = 1; m < 64; m <<= 1) {
            s  += __shfl_xor(s, m, 64);
            sq += __shfl_xor(sq, m, 64);
        }
        const int wave = tt >> 6;
        if ((tt & 63) == 0) { ss[wave] = s; ssq[wave] = sq; }
        __syncthreads();
        s  = ss[0] + ss[1] + ss[2] + ss[3];
        sq = ssq[0] + ssq[1] + ssq[2] + ssq[3];
        const float mean = s * (1.0f / DIMM);
        const float var  = sq * (1.0f / DIMM) - mean * mean;
        const float rs   = rsqrtf(var + 1e-5f);
        const float4 gv = ((const float4*)g)[tt];
        const float4 bv = ((const float4*)bb)[tt];
        bf16* o = lnout + (size_t)row * DIMM + tt * 4;
        o[0] = (bf16)((v.x - mean) * rs * gv.x + bv.x);
        o[1] = (bf16)((v.y - mean) * rs * gv.y + bv.y);
        o[2] = (bf16)((v.z - mean) * rs * gv.z + bv.z);
        o[3] = (bf16)((v.w - mean) * rs * gv.w + bv.w);
        return;
    }

    // ---- weight transpose+cast tile ----
    const float* src; bf16* dst; int K, N, nx;
    if (t < 3072)      { src = wqkv; dst = wqkvT; K = DIMM; N = QKV3; nx = 96;  }
    else if (t < 4096) { src = wout; dst = woutT; K = DIMM; N = DIMM; nx = 32; t -= 3072; }
    else if (t < 8192) { src = wff1; dst = wff1T; K = DIMM; N = FFD;  nx = 128; t -= 4096; }
    else               { src = wff2; dst = wff2T; K = FFD;  N = DIMM; nx = 32; t -= 8192; }
    const int k0 = (t / nx) * 32;
    const int n0 = (t - (t / nx) * nx) * 32;

    const int r = threadIdx.x >> 5;   // 0..7
    const int c = threadIdx.x & 31;
    #pragma unroll
    for (int i = 0; i < 4; ++i)
        tile[r + 8 * i][c] = src[(size_t)(k0 + r + 8 * i) * N + n0 + c];
    __syncthreads();
    #pragma unroll
    for (int i = 0; i < 4; ++i)
        dst[(size_t)(n0 + r + 8 * i) * K + k0 + c] = (bf16)tile[c][r + 8 * i];
}

// ---------------------------------------------------------------------------
// LayerNorm fp32 [NROWS][1024] -> bf16, one block per row (used for LN2)
// ---------------------------------------------------------------------------
__global__ __launch_bounds__(256) void ln_cast_kernel(
    const float* __restrict__ x, const float* __restrict__ g,
    const float* __restrict__ b, bf16* __restrict__ out)
{
    const int row = blockIdx.x;
    const int t = threadIdx.x;
    const float4 v = ((const float4*)(x + (size_t)row * DIMM))[t];
    float s  = v.x + v.y + v.z + v.w;
    float sq = v.x * v.x + v.y * v.y + v.z * v.z + v.w * v.w;
    #pragma unroll
    for (int m = 1; m < 64; m <<= 1) {
        s  += __shfl_xor(s, m, 64);
        sq += __shfl_xor(sq, m, 64);
    }
    __shared__ float ss[4], ssq[4];
    const int wave = t >> 6;
    if ((t & 63) == 0) { ss[wave] = s; ssq[wave] = sq; }
    __syncthreads();
    s  = ss[0] + ss[1] + ss[2] + ss[3];
    sq = ssq[0] + ssq[1] + ssq[2] + ssq[3];
    const float mean = s * (1.0f / DIMM);
    const float var  = sq * (1.0f / DIMM) - mean * mean;
    const float rs   = rsqrtf(var + 1e-5f);
    const float4 gv = ((const float4*)g)[t];
    const float4 bv = ((const float4*)b)[t];
    bf16* o = out + (size_t)row * DIMM + t * 4;
    o[0] = (bf16)((v.x - mean) * rs * gv.x + bv.x);
    o[1] = (bf16)((v.y - mean) * rs * gv.y + bv.y);
    o[2] = (bf16)((v.z - mean) * rs * gv.z + bv.z);
    o[3] = (bf16)((v.w - mean) * rs * gv.w + bv.w);
}

// ---------------------------------------------------------------------------
// 256x256 8-wave GEMM — 4-phase fine-interleaved schedule (r13/r14 proven).
// Used for FF1 only (grid 256 = exactly 1 block/CU).
// EPI: 2 = +bias, GELU, bf16 out
// ---------------------------------------------------------------------------
template<int EPI>
__global__ __launch_bounds__(512, 2)
void gemm256_kernel(const bf16* __restrict__ A, const bf16* __restrict__ BT,
                    const float* __restrict__ bias, bf16* __restrict__ C,
                    int M, int N, int K, int ld)
{
    __shared__ bf16 As_[2][2][8192];   // [dbuf][half][128 rows x 64 k]
    __shared__ bf16 Bs_[2][2][8192];
    const int nb = N >> 8;
    const int chunk = (int)gridDim.x >> 3;
    const int idx = ((int)blockIdx.x & 7) * chunk + ((int)blockIdx.x >> 3);
    const int bm = idx / nb, bn = idx - bm * nb;
    const int tm = bm << 8, tn = bn << 8;
    const int tid = threadIdx.x;
    const int lane = tid & 63, w = tid >> 6;   // 8 waves
    const int wr = w >> 2, wc = w & 3;
    const int lq = lane & 15, hk = lane >> 4;

    const int sr  = lane >> 3;
    const int sgo = (((lane & 7) ^ sr) << 3);
    const bf16* gA0 = A  + (size_t)(tm +       w * 8 + sr) * ld + sgo;
    const bf16* gA1 = A  + (size_t)(tm + 128 + w * 8 + sr) * ld + sgo;
    const bf16* gB0 = BT + (size_t)(tn +       w * 8 + sr) * ld + sgo;
    const bf16* gB1 = BT + (size_t)(tn + 128 + w * 8 + sr) * ld + sgo;
    const size_t l64 = (size_t)64 * ld;

#define STG_A0(D, T) do { const size_t ko_ = (size_t)(T) * 64;              \
        GLDS16(gA0 + ko_,       &As_[D][0][w * 512]);                       \
        GLDS16(gA0 + ko_ + l64, &As_[D][0][4096 + w * 512]); } while (0)
#define STG_A1(D, T) do { const size_t ko_ = (size_t)(T) * 64;              \
        GLDS16(gA1 + ko_,       &As_[D][1][w * 512]);                       \
        GLDS16(gA1 + ko_ + l64, &As_[D][1][4096 + w * 512]); } while (0)
#define STG_B0(D, T) do { const size_t ko_ = (size_t)(T) * 64;              \
        GLDS16(gB0 + ko_,       &Bs_[D][0][w * 512]);                       \
        GLDS16(gB0 + ko_ + l64, &Bs_[D][0][4096 + w * 512]); } while (0)
#define STG_B1(D, T) do { const size_t ko_ = (size_t)(T) * 64;              \
        GLDS16(gB1 + ko_,       &Bs_[D][1][w * 512]);                       \
        GLDS16(gB1 + ko_ + l64, &Bs_[D][1][4096 + w * 512]); } while (0)

    f32x4 acc[8][4] = {};
    const int NT = K >> 6;

    STG_A0(0, 0); STG_B1(0, 0); STG_B0(0, 0); STG_A1(0, 0);
    STG_B0(1, 1); STG_A1(1, 1);

    for (int t = 0; t < NT; ++t) {
        const int d = t & 1, e = d ^ 1;
        if (t == NT - 1) asm volatile("s_waitcnt vmcnt(0)" ::: "memory");
        else             asm volatile("s_waitcnt vmcnt(4)" ::: "memory");
        __builtin_amdgcn_s_barrier();
        MEMFENCE;

        const char* Ah0 = (const char*)&As_[d][0][0];
        const char* Ah1 = (const char*)&As_[d][1][0];
        const char* Bh0 = (const char*)&Bs_[d][0][0];
        const char* Bh1 = (const char*)&Bs_[d][1][0];
        bf16x8 af[4][2], bfv[2][2];

#define DO_MFMA(MH, NH) do {                                                 \
        __builtin_amdgcn_s_setprio(1);                                       \
        _Pragma("unroll")                                                    \
        for (int mi = 0; mi < 4; ++mi)                                       \
            _Pragma("unroll")                                                \
            for (int nj = 0; nj < 2; ++nj)                                   \
                _Pragma("unroll")                                            \
                for (int kk = 0; kk < 2; ++kk)                               \
                    acc[(MH)*4+mi][(NH)*2+nj] =                              \
                        mfma16(bfv[nj][kk], af[mi][kk], acc[(MH)*4+mi][(NH)*2+nj]); \
        __builtin_amdgcn_s_setprio(0); } while (0)

        {   // ph1 (0,0)
            #pragma unroll
            for (int mi = 0; mi < 4; ++mi) {
                const int lr = wr * 64 + mi * 16 + lq;
                af[mi][0] = *(const bf16x8*)(Ah0 + lr * 128 + ((hk ^ (lr & 7)) << 4));
                af[mi][1] = *(const bf16x8*)(Ah0 + lr * 128 + (((4 + hk) ^ (lr & 7)) << 4));
            }
            #pragma unroll
            for (int nj = 0; nj < 2; ++nj) {
                const int lc = wc * 32 + nj * 16 + lq;
                bfv[nj][0] = *(const bf16x8*)(Bh0 + lc * 128 + ((hk ^ (lc & 7)) << 4));
                bfv[nj][1] = *(const bf16x8*)(Bh0 + lc * 128 + (((4 + hk) ^ (lc & 7)) << 4));
            }
            if (t + 1 < NT) STG_A0(e, t + 1);
            DO_MFMA(0, 0);
        }
        MEMFENCE; __builtin_amdgcn_s_barrier(); MEMFENCE;
        {   // ph2 (1,0)
            #pragma unroll
            for (int mi = 0; mi < 4; ++mi) {
                const int lr = wr * 64 + mi * 16 + lq;
                af[mi][0] = *(const bf16x8*)(Ah1 + lr * 128 + ((hk ^ (lr & 7)) << 4));
                af[mi][1] = *(const bf16x8*)(Ah1 + lr * 128 + (((4 + hk) ^ (lr & 7)) << 4));
            }
            if (t + 1 < NT) STG_B1(e, t + 1);
            DO_MFMA(1, 0);
        }
        MEMFENCE; __builtin_amdgcn_s_barrier(); MEMFENCE;
        {   // ph3 (1,1)
            #pragma unroll
            for (int nj = 0; nj < 2; ++nj) {
                const int lc = wc * 32 + nj * 16 + lq;
                bfv[nj][0] = *(const bf16x8*)(Bh1 + lc * 128 + ((hk ^ (lc & 7)) << 4));
                bfv[nj][1] = *(const bf16x8*)(Bh1 + lc * 128 + (((4 + hk) ^ (lc & 7)) << 4));
            }
            if (t + 2 < NT) STG_B0(d, t + 2);
            DO_MFMA(1, 1);
        }
        MEMFENCE; __builtin_amdgcn_s_barrier(); MEMFENCE;
        {   // ph4 (0,1)
            #pragma unroll
            for (int mi = 0; mi < 4; ++mi) {
                const int lr = wr * 64 + mi * 16 + lq;
                af[mi][0] = *(const bf16x8*)(Ah0 + lr * 128 + ((hk ^ (lr & 7)) << 4));
                af[mi][1] = *(const bf16x8*)(Ah0 + lr * 128 + (((4 + hk) ^ (lr & 7)) << 4));
            }
            if (t + 2 < NT) STG_A1(d, t + 2);
            DO_MFMA(0, 1);
        }
        MEMFENCE; __builtin_amdgcn_s_barrier(); MEMFENCE;
#undef DO_MFMA
    }
#undef STG_A0
#undef STG_A1
#undef STG_B0
#undef STG_B1

    #pragma unroll
    for (int i = 0; i < 8; ++i) {
        const int mh = i >> 2, mi = i & 3;
        const int row = tm + mh * 128 + wr * 64 + mi * 16 + lq;
        #pragma unroll
        for (int j = 0; j < 4; ++j) {
            const int nh = j >> 1, nj = j & 1;
            const int col = tn + nh * 128 + wc * 32 + nj * 16 + (hk << 2);
            if (EPI == 0) {
                bf16x4 pk = { (bf16)acc[i][j][0], (bf16)acc[i][j][1],
                              (bf16)acc[i][j][2], (bf16)acc[i][j][3] };
                *(bf16x4*)(C + (size_t)row * N + col) = pk;
            } else {
                const float4 bv4 = *(const float4*)(bias + col);
                float v0 = acc[i][j][0] + bv4.x, v1 = acc[i][j][1] + bv4.y;
                float v2 = acc[i][j][2] + bv4.z, v3 = acc[i][j][3] + bv4.w;
                bf16x4 pk = {
                    (bf16)(0.5f * v0 * (1.0f + erff(v0 * 0.70710678118654752f))),
                    (bf16)(0.5f * v1 * (1.0f + erff(v1 * 0.70710678118654752f))),
                    (bf16)(0.5f * v2 * (1.0f + erff(v2 * 0.70710678118654752f))),
                    (bf16)(0.5f * v3 * (1.0f + erff(v3 * 0.70710678118654752f))) };
                *(bf16x4*)(C + (size_t)row * N + col) = pk;
            }
        }
    }
}

// ---------------------------------------------------------------------------
// 128x128 3-stage counted-vmcnt GEMM + swapped-operand vectorized epilogue.
// Used for QKV (768 blk, 3/CU), out-proj, FF2 split-K.
// EPI: 0 = bf16 out; 1 = +bias +residual, fp32 out; 3 = split-K partial (BF16)
// ---------------------------------------------------------------------------
template<int EPI>
__global__ __launch_bounds__(256, 3)
void gemm_bt_kernel(const bf16* __restrict__ A, const bf16* __restrict__ BT,
                    const float* __restrict__ bias, const float* __restrict__ res,
                    void* __restrict__ Cout, int M, int N, int K, int ld)
{
    __shared__ bf16 As[3][4096];   // [buf][128 m][32 k]
    __shared__ bf16 Bs[3][4096];
    const int nb = N >> 7;
    const int chunk = (int)gridDim.x >> 3;
    int idx = (blockIdx.x & 7) * chunk + (blockIdx.x >> 3);
    int ks = 0;
    if (EPI == 3) {
        const int tiles = (M >> 7) * nb;
        ks = idx / tiles;
        idx -= ks * tiles;
    }
    const int bm = idx / nb, bn = idx - bm * nb;
    const int tm = bm << 7, tn = bn << 7;
    const int tid = threadIdx.x;
    const int lane = tid & 63, wave = tid >> 6;
    const int wm = (wave >> 1) << 6, wn = (wave & 1) << 6;
    const int kofs = ks * K;

    const bf16* ga = A  + (size_t)(tm + wave * 32 + (lane >> 2)) * ld + kofs + ((lane & 3) << 3);
    const bf16* gb = BT + (size_t)(tn + wave * 32 + (lane >> 2)) * ld + kofs + ((lane & 3) << 3);
    const size_t k16 = (size_t)16 * ld;

    f32x4 acc[4][4] = {};
    const int ro = (lane & 15) * 32 + ((lane >> 4) << 3);

#define GSTAGE(BUF, KO) do {                          \
        bf16* la_ = &As[BUF][wave * 1024];            \
        bf16* lb_ = &Bs[BUF][wave * 1024];            \
        GLDS16(ga + (KO),       la_);                 \
        GLDS16(ga + (KO) + k16, la_ + 512);           \
        GLDS16(gb + (KO),       lb_);                 \
        GLDS16(gb + (KO) + k16, lb_ + 512);           \
    } while (0)

    GSTAGE(0, 0);
    GSTAGE(1, 32);
    GSTAGE(2, 64);
    int cur = 0;
    for (int k0 = 0; k0 < K; k0 += 32) {
        if (k0 + 96 <= K)      asm volatile("s_waitcnt vmcnt(8)" ::: "memory");
        else if (k0 + 64 <= K) asm volatile("s_waitcnt vmcnt(4)" ::: "memory");
        else                   asm volatile("s_waitcnt vmcnt(0)" ::: "memory");
        __builtin_amdgcn_s_barrier();

        bf16x8 af[4], bfr[4];
        #pragma unroll
        for (int i = 0; i < 4; ++i) {
            af[i]  = *(const bf16x8*)(&As[cur][0] + (wm + i * 16) * 32 + ro);
            bfr[i] = *(const bf16x8*)(&Bs[cur][0] + (wn + i * 16) * 32 + ro);
        }
        #pragma unroll
        for (int i = 0; i < 4; ++i)
            #pragma unroll
            for (int j = 0; j < 4; ++j)
                acc[i][j] = mfma16(bfr[j], af[i], acc[i][j]);   // swapped

        MEMFENCE;
        __builtin_amdgcn_s_barrier();
        MEMFENCE;
        if (k0 + 96 < K) GSTAGE(cur, k0 + 96);
        cur = (cur == 2) ? 0 : cur + 1;
    }
#undef GSTAGE

    // swapped layout: acc[i][j][r] = C[tm+wm+i*16+lq][tn+wn+j*16+hk*4+r]
    const int lq = lane & 15, hk = lane >> 4;
    const int r0 = tm + wm + lq;
    const int c0 = tn + wn + (hk << 2);
    if (EPI == 0) {
        bf16* C = (bf16*)Cout;
        #pragma unroll
        for (int j = 0; j < 4; ++j)
            #pragma unroll
            for (int i = 0; i < 4; ++i) {
                bf16x4 pk = { (bf16)acc[i][j][0], (bf16)acc[i][j][1],
                              (bf16)acc[i][j][2], (bf16)acc[i][j][3] };
                *(bf16x4*)(C + (size_t)(r0 + i * 16) * N + c0 + j * 16) = pk;
            }
    } else if (EPI == 1) {
        float* C = (float*)Cout;
        #pragma unroll
        for (int j = 0; j < 4; ++j) {
            const float4 bv4 = *(const float4*)(bias + c0 + j * 16);
            #pragma unroll
            for (int i = 0; i < 4; ++i) {
                const size_t off = (size_t)(r0 + i * 16) * N + c0 + j * 16;
                const float4 rv = *(const float4*)(res + off);
                float4 o;
                o.x = acc[i][j][0] + bv4.x + rv.x;
                o.y = acc[i][j][1] + bv4.y + rv.y;
                o.z = acc[i][j][2] + bv4.z + rv.z;
                o.w = acc[i][j][3] + bv4.w + rv.w;
                *(float4*)(C + off) = o;
            }
        }
    } else {   // EPI == 3: BF16 partial, slice ks (halves partial HBM traffic)
        bf16* C = (bf16*)(ks == 0 ? Cout : (void*)res);
        #pragma unroll
        for (int j = 0; j < 4; ++j)
            #pragma unroll
            for (int i = 0; i < 4; ++i) {
                bf16x4 pk = { (bf16)acc[i][j][0], (bf16)acc[i][j][1],
                              (bf16)acc[i][j][2], (bf16)acc[i][j][3] };
                *(bf16x4*)(C + (size_t)(r0 + i * 16) * N + c0 + j * 16) = pk;
            }
    }
}

// ---------------------------------------------------------------------------
// FF2 split-K reduce: out = p0 + p1 + bias + res  (p0/p1 BF16, rest fp32)
// ---------------------------------------------------------------------------
__global__ __launch_bounds__(256) void ff2_reduce_kernel(
    const bf16* __restrict__ p0, const bf16* __restrict__ p1,
    const float* __restrict__ bias, const float* __restrict__ res,
    float* __restrict__ out)
{
    const int i = blockIdx.x * 256 + threadIdx.x;    // float4 / bf16x4 index
    const bf16x4 a = ((const bf16x4*)p0)[i];
    const bf16x4 b = ((const bf16x4*)p1)[i];
    const float4 r = ((const float4*)res)[i];
    const float4 g = ((const float4*)bias)[i & 255];
    float4 o;
    o.x = (float)a[0] + (float)b[0] + r.x + g.x;
    o.y = (float)a[1] + (float)b[1] + r.y + g.y;
    o.z = (float)a[2] + (float)b[2] + r.z + g.z;
    o.w = (float)a[3] + (float)b[3] + r.w + g.w;
    ((float4*)out)[i] = o;
}

// ---------------------------------------------------------------------------
// V transpose per head, PERMUTED columns (r18 proven): within each 32-column
// block, position n' holds V column n with
//   n' = (n&3) | ((n>>4)&1)<<2 | ((n>>2)&3)<<3
// ---------------------------------------------------------------------------
__global__ __launch_bounds__(256) void vtrans_kernel(
    const bf16* __restrict__ qkv, bf16* __restrict__ vT)
{
    __shared__ bf16 t[64 * 64];
    const int n0 = blockIdx.x * 64;
    const int bh = blockIdx.y;
    const int b = bh >> 4, h = bh & 15;
    const bf16* src = qkv + (size_t)(b * SEQ + n0) * QKV3 + 2 * DIMM + h * DHEAD;

    #pragma unroll
    for (int it = 0; it < 2; ++it) {
        const int c = it * 256 + threadIdx.x;
        const int n = c >> 3, d8 = (c & 7) * 8;
        const bf16x8 v8 = *(const bf16x8*)(src + (size_t)n * QKV3 + d8);
        const int byte = (n * 128 + d8 * 2) ^ (((n >> 3) & 7) << 4);
        *(bf16x8*)((char*)t + byte) = v8;
    }
    __syncthreads();
    #pragma unroll
    for (int it = 0; it < 2; ++it) {
        const int c = it * 256 + threadIdx.x;
        const int d = c >> 3, nc = c & 7;
        bf16x8 o8;
        #pragma unroll
        for (int i = 0; i < 8; ++i) {
            const int n = nc * 8 + i;
            const int byte = (n * 128 + d * 2) ^ ((nc & 7) << 4);
            o8[i] = *(const bf16*)((const char*)t + byte);
        }
        bf16* dstrow = vT + (size_t)bh * DHEAD * SEQ + (size_t)d * SEQ;
        #pragma unroll
        for (int half = 0; half < 2; ++half) {
            const int nb2 = nc * 8 + half * 4;
            const int nabs = n0 + nb2;
            const int off = nb2 & 31;
            const int offp = (((off >> 4) & 1) << 2) | (((off >> 2) & 3) << 3);
            bf16x4 q4 = { o8[half * 4 + 0], o8[half * 4 + 1],
                          o8[half * 4 + 2], o8[half * 4 + 3] };
            *(bf16x4*)(dstrow + (nabs & ~31) + offp) = q4;
        }
    }
}

// ---------------------------------------------------------------------------
// Flash attention v8 (r19/r21-proven, 61 us best): P-in-register PV with
// permuted vT', 2x unrolled K-loop (compile-time buffer indices), lane-local
// l with epilogue reduction.
// ---------------------------------------------------------------------------
struct AttnState { float m, l; f32x4 o[4]; };

static __device__ __forceinline__ void attn_body(
    const bf16* __restrict__ Kbuf, const bf16* __restrict__ Vbuf,
    const bf16x8* __restrict__ qf, int q, int hi, AttnState& st)
{
    // S^T = K Q^T : sv[kf][r] = S[kv=kf*16+hi*4+r][q]
    f32x4 sv[4];
    __builtin_amdgcn_s_setprio(1);
    #pragma unroll
    for (int kf = 0; kf < 4; ++kf) {
        f32x4 z = {0.f, 0.f, 0.f, 0.f};
        sv[kf] = z;
        #pragma unroll
        for (int ks = 0; ks < 2; ++ks) {
            const int row = kf * 16 + q;
            const int bo = (row * 128 + ks * 64 + (hi << 4)) ^ ((row & 7) << 4);
            const bf16x8 kfrag = *(const bf16x8*)((const char*)Kbuf + bo);
            sv[kf] = mfma16(kfrag, qf[ks], sv[kf]);
        }
    }
    __builtin_amdgcn_s_setprio(0);

    float pmax;
    {
        float a = fmaxf(fmaxf(sv[0][0], sv[0][1]), fmaxf(sv[0][2], sv[0][3]));
        float b2 = fmaxf(fmaxf(sv[1][0], sv[1][1]), fmaxf(sv[1][2], sv[1][3]));
        float c = fmaxf(fmaxf(sv[2][0], sv[2][1]), fmaxf(sv[2][2], sv[2][3]));
        float d = fmaxf(fmaxf(sv[3][0], sv[3][1]), fmaxf(sv[3][2], sv[3][3]));
        pmax = fmaxf(fmaxf(a, b2), fmaxf(c, d));
    }
    pmax = fmaxf(pmax, __shfl_xor(pmax, 16, 64));
    pmax = fmaxf(pmax, __shfl_xor(pmax, 32, 64));

    if (__any(pmax - st.m > 8.0f)) {
        const float nm = fmaxf(st.m, pmax);
        const float fr = __expf(st.m - nm);
        st.l *= fr;
        #pragma unroll
        for (int df = 0; df < 4; ++df) {
            st.o[df][0] *= fr; st.o[df][1] *= fr;
            st.o[df][2] *= fr; st.o[df][3] *= fr;
        }
        st.m = nm;
    }

    // P = exp(S - m), lane-local l accumulation (reduced in epilogue)
    float pv[4][4];
    float rsum = 0.0f;
    #pragma unroll
    for (int kf = 0; kf < 4; ++kf)
        #pragma unroll
        for (int r = 0; r < 4; ++r) {
            pv[kf][r] = __expf(sv[kf][r] - st.m);
            rsum += pv[kf][r];
        }
    st.l += rsum;

    // pack P into PV B-operands (permuted-k)
    bf16x8 pb[2];
    #pragma unroll
    for (int ks = 0; ks < 2; ++ks)
        #pragma unroll
        for (int r = 0; r < 4; ++r) {
            pb[ks][r]     = (bf16)pv[2 * ks][r];
            pb[ks][r + 4] = (bf16)pv[2 * ks + 1][r];
        }

    // O^T += V^T P^T : conflict-free b128 A-read (permutation baked in vT')
    __builtin_amdgcn_s_setprio(1);
    #pragma unroll
    for (int df = 0; df < 4; ++df) {
        const int rowv = df * 16 + q;
        #pragma unroll
        for (int ks = 0; ks < 2; ++ks) {
            const int bo = (rowv * 128 + ks * 64 + (hi << 4)) ^ ((rowv & 7) << 4);
            const bf16x8 vfrag = *(const bf16x8*)((const char*)Vbuf + bo);
            st.o[df] = mfma16(vfrag, pb[ks], st.o[df]);
        }
    }
    __builtin_amdgcn_s_setprio(0);
}

__global__ __launch_bounds__(256, 4)
void attn_kernel(const bf16* __restrict__ qkv, const bf16* __restrict__ vT,
                 bf16* __restrict__ out)
{
    __shared__ bf16 Ks[2][64 * 64];
    __shared__ bf16 Vs[2][64 * 64];
    const int bid = blockIdx.x;
    const int idx = (bid & 7) * 128 + (bid >> 3);
    const int qt = idx & 31;
    const int bh = idx >> 5;
    const int b = bh >> 4, h = bh & 15;
    const int tid = threadIdx.x;
    const int lane = tid & 63, wave = tid >> 6;
    const int q = lane & 15, hi = lane >> 4;

    const bf16* qbase = qkv + (size_t)(b * SEQ) * QKV3 + h * DHEAD;
    const bf16* kbase = qbase + DIMM;
    const bf16* vbase = vT + (size_t)bh * DHEAD * SEQ;

    const int q0 = qt * 64 + wave * 16;
    bf16x8 qf[2];
    {
        const bf16* qp = qbase + (size_t)(q0 + q) * QKV3 + (hi << 3);
        qf[0] = *(const bf16x8*)qp;
        qf[1] = *(const bf16x8*)(qp + 32);
        #pragma unroll
        for (int j = 0; j < 8; ++j) {
            qf[0][j] = (bf16)((float)qf[0][j] * 0.125f);
            qf[1][j] = (bf16)((float)qf[1][j] * 0.125f);
        }
    }

    const int srow = lane >> 3;
    const int scol = ((lane & 7) ^ srow) << 3;
    const bf16* gk = kbase + (size_t)(wave * 16 + srow) * QKV3 + scol;
    const bf16* gv = vbase + (size_t)(wave * 16 + srow) * SEQ + scol;

#define STAGE(BUF, KT) do {                                        \
        bf16* lk_ = &Ks[BUF][wave * 1024];                         \
        bf16* lv_ = &Vs[BUF][wave * 1024];                         \
        GLDS16(gk + (size_t)(KT) * QKV3,       lk_);               \
        GLDS16(gk + (size_t)((KT) + 8) * QKV3, lk_ + 512);         \
        GLDS16(gv + (KT),                      lv_);               \
        GLDS16(gv + (KT) + 8 * SEQ,            lv_ + 512);         \
    } while (0)

    AttnState st;
    st.m = -1e30f; st.l = 0.0f;
    #pragma unroll
    for (int df = 0; df < 4; ++df) {
        f32x4 z = {0.f, 0.f, 0.f, 0.f};
        st.o[df] = z;
    }

    STAGE(0, 0);
    for (int kt = 0; kt < SEQ; kt += 128) {
        __syncthreads();                       // drains: STAGE(kt) resident
        STAGE(1, kt + 64);                     // always in range (kt+64 <= SEQ-64)
        attn_body(&Ks[0][0], &Vs[0][0], qf, q, hi, st);
        __syncthreads();                       // drains: STAGE(kt+64) resident
        if (kt + 128 < SEQ) STAGE(0, kt + 128);
        attn_body(&Ks[1][0], &Vs[1][0], qf, q, hi, st);
    }
#undef STAGE

    {
        float lt = st.l;
        lt += __shfl_xor(lt, 16, 64);
        lt += __shfl_xor(lt, 32, 64);
        const float inv = 1.0f / lt;
        const int grow = b * SEQ + q0 + q;
        #pragma unroll
        for (int df = 0; df < 4; ++df) {
            bf16x4 pk = { (bf16)(st.o[df][0] * inv), (bf16)(st.o[df][1] * inv),
                          (bf16)(st.o[df][2] * inv), (bf16)(st.o[df][3] * inv) };
            *(bf16x4*)(out + (size_t)grow * DIMM + h * DHEAD + df * 16 + hi * 4) = pk;
        }
    }
}

// ---------------------------------------------------------------------------
extern "C" void kernel_launch(void* const* d_in, const int* in_sizes, int n_in,
                              void* d_out, int out_size, void* d_ws, size_t ws_size,
                              hipStream_t stream)
{
    (void)in_sizes; (void)n_in; (void)out_size;
    const float* x    = (const float*)d_in[0];
    const float* ln1g = (const float*)d_in[1];
    const float* ln1b = (const float*)d_in[2];
    const float* ln2g = (const float*)d_in[3];
    const float* ln2b = (const float*)d_in[4];
    const float* wqkv = (const float*)d_in[5];
    const float* wout = (const float*)d_in[6];
    const float* bout = (const float*)d_in[7];
    const float* wff1 = (const float*)d_in[8];
    const float* bff1 = (const float*)d_in[9];
    const float* wff2 = (const float*)d_in[10];
    const float* bff2 = (const float*)d_in[11];

    char* ws = (char*)d_ws;
    const dim3 blk(256);
    const dim3 blk512(512);
    const bool splitk = ws_size >= 92274688ULL;   // 88 MB packed layout

    if (splitk) {
        bf16*  wff2T = (bf16*)(ws);
        bf16*  woutT = (bf16*)(ws + 8388608);
        bf16*  wff1T = (bf16*)(ws + 10485760);
        bf16*  wqkvT = (bf16*)(ws + 18874368);
        bf16*  hbuf  = (bf16*)(ws + 25165824);
        bf16*  qkvb  = (bf16*)(ws + 33554432);
        bf16*  vT    = (bf16*)(ws + 58720256);
        bf16*  attnb = (bf16*)(ws + 67108864);
        float* x2    = (float*)(ws + 75497472);
        bf16*  fbuf  = (bf16*)(ws + 41943040);
        bf16*  p0    = (bf16*)(ws + 8388608);     // 8 MB bf16 partial (dead woutT/wff1T)
        bf16*  p1    = (bf16*)(ws + 25165824);    // 8 MB bf16 partial (dead hbuf)

        prep_kernel<<<dim3(16384), blk, 0, stream>>>(
            wqkv, wqkvT, wout, woutT, wff1, wff1T, wff2, wff2T,
            x, ln1g, ln1b, hbuf);
        gemm_bt_kernel<0><<<(NROWS / 128) * (QKV3 / 128), blk, 0, stream>>>(
            hbuf, wqkvT, nullptr, nullptr, qkvb, NROWS, QKV3, DIMM, DIMM);
        vtrans_kernel<<<dim3(SEQ / 64, BATCH * NHEAD), blk, 0, stream>>>(qkvb, vT);
        attn_kernel<<<dim3(1024), blk, 0, stream>>>(qkvb, vT, attnb);
        gemm_bt_kernel<1><<<(NROWS / 128) * (DIMM / 128), blk, 0, stream>>>(
            attnb, woutT, bout, x, x2, NROWS, DIMM, DIMM, DIMM);
        ln_cast_kernel<<<NROWS, blk, 0, stream>>>(x2, ln2g, ln2b, hbuf);
        gemm256_kernel<2><<<(NROWS / 256) * (FFD / 256), blk512, 0, stream>>>(
            hbuf, wff1T, bff1, fbuf, NROWS, FFD, DIMM, DIMM);
        gemm_bt_kernel<3><<<2 * (NROWS / 128) * (DIMM / 128), blk, 0, stream>>>(
            fbuf, wff2T, nullptr, (const float*)p1, p0, NROWS, DIMM, FFD / 2, FFD);
        ff2_reduce_kernel<<<(NROWS * DIMM) / 1024, blk, 0, stream>>>(
            p0, p1, bff2, x2, (float*)d_out);
    } else {
        bf16*  wqkvT = (bf16*)(ws);
        bf16*  woutT = (bf16*)(ws + 6291456);
        bf16*  wff1T = (bf16*)(ws + 8388608);
        bf16*  wff2T = (bf16*)(ws + 16777216);
        float* x2    = (float*)(ws + 25165824);
        bf16*  vT    = (bf16*)(ws + 25165824);
        bf16*  hbuf  = (bf16*)(ws + 41943040);
        bf16*  qkvb  = (bf16*)(ws + 50331648);
        bf16*  attnb = (bf16*)(ws + 75497472);
        bf16*  fbuf  = (bf16*)(ws + 50331648);

        prep_kernel<<<dim3(16384), blk, 0, stream>>>(
            wqkv, wqkvT, wout, woutT, wff1, wff1T, wff2, wff2T,
            x, ln1g, ln1b, hbuf);
        gemm_bt_kernel<0><<<(NROWS / 128) * (QKV3 / 128), blk, 0, stream>>>(
            hbuf, wqkvT, nullptr, nullptr, qkvb, NROWS, QKV3, DIMM, DIMM);
        vtrans_kernel<<<dim3(SEQ / 64, BATCH * NHEAD), blk, 0, stream>>>(qkvb, vT);
        attn_kernel<<<dim3(1024), blk, 0, stream>>>(qkvb, vT, attnb);
        gemm_bt_kernel<1><<<(NROWS / 128) * (DIMM / 128), blk, 0, stream>>>(
            attnb, woutT, bout, x, x2, NROWS, DIMM, DIMM, DIMM);
        ln_cast_kernel<<<NROWS, blk, 0, stream>>>(x2, ln2g, ln2b, hbuf);
        gemm256_kernel<2><<<(NROWS / 256) * (FFD / 256), blk512, 0, stream>>>(
            hbuf, wff1T, bff1, fbuf, NROWS, FFD, DIMM, DIMM);
        gemm_bt_kernel<1><<<(NROWS / 128) * (DIMM / 128), blk, 0, stream>>>(
            fbuf, wff2T, bff2, x2, (float*)d_out, NROWS, DIMM, FFD, FFD);
    }
}

// Round 24
// 247.877 us; speedup vs baseline: 1.0318x; 1.0113x over previous
//
#include <hip/hip_runtime.h>
#include <hip/hip_bf16.h>
#include <math.h>

#define SEQ   2048
#define BATCH 2
#define NROWS 4096      /* BATCH*SEQ */
#define DIMM  1024
#define QKV3  3072
#define FFD   4096
#define NHEAD 16
#define DHEAD 64

typedef __bf16 bf16;
typedef __bf16 bf16x4 __attribute__((ext_vector_type(4)));
typedef __bf16 bf16x8 __attribute__((ext_vector_type(8)));
typedef float  f32x4  __attribute__((ext_vector_type(4)));

static __device__ __forceinline__ f32x4 mfma16(bf16x8 a, bf16x8 b, f32x4 c) {
    return __builtin_amdgcn_mfma_f32_16x16x32_bf16(a, b, c, 0, 0, 0);
}

#define GLDS16(gp, lp) __builtin_amdgcn_global_load_lds( \
    (__attribute__((address_space(1))) void*)(gp),       \
    (__attribute__((address_space(3))) void*)(lp), 16, 0, 0)

#define MEMFENCE asm volatile("" ::: "memory")

// ---------------------------------------------------------------------------
// PREP kernel: merged weight transpose+cast (12288 tile-blocks) AND LayerNorm1
// (4096 row-blocks) in ONE launch (r22 proven).
// ---------------------------------------------------------------------------
__global__ __launch_bounds__(256) void prep_kernel(
    const float* __restrict__ wqkv, bf16* __restrict__ wqkvT,
    const float* __restrict__ wout, bf16* __restrict__ woutT,
    const float* __restrict__ wff1, bf16* __restrict__ wff1T,
    const float* __restrict__ wff2, bf16* __restrict__ wff2T,
    const float* __restrict__ x, const float* __restrict__ g,
    const float* __restrict__ bb, bf16* __restrict__ lnout)
{
    __shared__ float tile[32][33];
    __shared__ float ss[4], ssq[4];
    int t = blockIdx.x;

    if (t >= 12288) {
        // ---- LayerNorm row (t - 12288) ----
        const int row = t - 12288;
        const int tt = threadIdx.x;
        const float4 v = ((const float4*)(x + (size_t)row * DIMM))[tt];
        float s  = v.x + v.y + v.z + v.w;
        float sq = v.x * v.x + v.y * v.y + v.z * v.z + v.w * v.w;
        #pragma unroll
        for (int m = 1; m < 64; m <<= 1) {
            s  += __shfl_xor(s, m, 64);
            sq += __shfl_xor(sq, m, 64);
        }
        const int wave = tt >> 6;
        if ((tt & 63) == 0) { ss[wave] = s; ssq[wave] = sq; }
        __syncthreads();
        s  = ss[0] + ss[1] + ss[2] + ss[3];
        sq = ssq[0] + ssq[1] + ssq[2] + ssq[3];
        const float mean = s * (1.0f / DIMM);
        const float var  = sq * (1.0f / DIMM) - mean * mean;
        const float rs   = rsqrtf(var + 1e-5f);
        const float4 gv = ((const float4*)g)[tt];
        const float4 bv = ((const float4*)bb)[tt];
        bf16* o = lnout + (size_t)row * DIMM + tt * 4;
        o[0] = (bf16)((v.x - mean) * rs * gv.x + bv.x);
        o[1] = (bf16)((v.y - mean) * rs * gv.y + bv.y);
        o[2] = (bf16)((v.z - mean) * rs * gv.z + bv.z);
        o[3] = (bf16)((v.w - mean) * rs * gv.w + bv.w);
        return;
    }

    // ---- weight transpose+cast tile ----
    const float* src; bf16* dst; int K, N, nx;
    if (t < 3072)      { src = wqkv; dst = wqkvT; K = DIMM; N = QKV3; nx = 96;  }
    else if (t < 4096) { src = wout; dst = woutT; K = DIMM; N = DIMM; nx = 32; t -= 3072; }
    else if (t < 8192) { src = wff1; dst = wff1T; K = DIMM; N = FFD;  nx = 128; t -= 4096; }
    else               { src = wff2; dst = wff2T; K = FFD;  N = DIMM; nx = 32; t -= 8192; }
    const int k0 = (t / nx) * 32;
    const int n0 = (t - (t / nx) * nx) * 32;

    const int r = threadIdx.x >> 5;   // 0..7
    const int c = threadIdx.x & 31;
    #pragma unroll
    for (int i = 0; i < 4; ++i)
        tile[r + 8 * i][c] = src[(size_t)(k0 + r + 8 * i) * N + n0 + c];
    __syncthreads();
    #pragma unroll
    for (int i = 0; i < 4; ++i)
        dst[(size_t)(n0 + r + 8 * i) * K + k0 + c] = (bf16)tile[c][r + 8 * i];
}

// ---------------------------------------------------------------------------
// LayerNorm fp32 [NROWS][1024] -> bf16 (fallback path LN2)
// ---------------------------------------------------------------------------
__global__ __launch_bounds__(256) void ln_cast_kernel(
    const float* __restrict__ x, const float* __restrict__ g,
    const float* __restrict__ b, bf16* __restrict__ out)
{
    const int row = blockIdx.x;
    const int t = threadIdx.x;
    const float4 v = ((const float4*)(x + (size_t)row * DIMM))[t];
    float s  = v.x + v.y + v.z + v.w;
    float sq = v.x * v.x + v.y * v.y + v.z * v.z + v.w * v.w;
    #pragma unroll
    for (int m = 1; m < 64; m <<= 1) {
        s  += __shfl_xor(s, m, 64);
        sq += __shfl_xor(sq, m, 64);
    }
    __shared__ float ss[4], ssq[4];
    const int wave = t >> 6;
    if ((t & 63) == 0) { ss[wave] = s; ssq[wave] = sq; }
    __syncthreads();
    s  = ss[0] + ss[1] + ss[2] + ss[3];
    sq = ssq[0] + ssq[1] + ssq[2] + ssq[3];
    const float mean = s * (1.0f / DIMM);
    const float var  = sq * (1.0f / DIMM) - mean * mean;
    const float rs   = rsqrtf(var + 1e-5f);
    const float4 gv = ((const float4*)g)[t];
    const float4 bv = ((const float4*)b)[t];
    bf16* o = out + (size_t)row * DIMM + t * 4;
    o[0] = (bf16)((v.x - mean) * rs * gv.x + bv.x);
    o[1] = (bf16)((v.y - mean) * rs * gv.y + bv.y);
    o[2] = (bf16)((v.z - mean) * rs * gv.z + bv.z);
    o[3] = (bf16)((v.w - mean) * rs * gv.w + bv.w);
}

// ---------------------------------------------------------------------------
// LayerNorm BF16 input [NROWS][1024] -> bf16 (splitk path LN2, x2 in bf16)
// ---------------------------------------------------------------------------
__global__ __launch_bounds__(256) void ln_cast_b_kernel(
    const bf16* __restrict__ x, const float* __restrict__ g,
    const float* __restrict__ b, bf16* __restrict__ out)
{
    const int row = blockIdx.x;
    const int t = threadIdx.x;
    const bf16x4 v4 = ((const bf16x4*)(x + (size_t)row * DIMM))[t];
    const float vx = (float)v4[0], vy = (float)v4[1];
    const float vz = (float)v4[2], vw = (float)v4[3];
    float s  = vx + vy + vz + vw;
    float sq = vx * vx + vy * vy + vz * vz + vw * vw;
    #pragma unroll
    for (int m = 1; m < 64; m <<= 1) {
        s  += __shfl_xor(s, m, 64);
        sq += __shfl_xor(sq, m, 64);
    }
    __shared__ float ss[4], ssq[4];
    const int wave = t >> 6;
    if ((t & 63) == 0) { ss[wave] = s; ssq[wave] = sq; }
    __syncthreads();
    s  = ss[0] + ss[1] + ss[2] + ss[3];
    sq = ssq[0] + ssq[1] + ssq[2] + ssq[3];
    const float mean = s * (1.0f / DIMM);
    const float var  = sq * (1.0f / DIMM) - mean * mean;
    const float rs   = rsqrtf(var + 1e-5f);
    const float4 gv = ((const float4*)g)[t];
    const float4 bv = ((const float4*)b)[t];
    bf16* o = out + (size_t)row * DIMM + t * 4;
    o[0] = (bf16)((vx - mean) * rs * gv.x + bv.x);
    o[1] = (bf16)((vy - mean) * rs * gv.y + bv.y);
    o[2] = (bf16)((vz - mean) * rs * gv.z + bv.z);
    o[3] = (bf16)((vw - mean) * rs * gv.w + bv.w);
}

// ---------------------------------------------------------------------------
// 256x256 8-wave GEMM — 4-phase fine-interleaved schedule (r13/r14 proven).
// Used for FF1 only (grid 256 = exactly 1 block/CU).
// EPI: 2 = +bias, GELU, bf16 out
// ---------------------------------------------------------------------------
template<int EPI>
__global__ __launch_bounds__(512, 2)
void gemm256_kernel(const bf16* __restrict__ A, const bf16* __restrict__ BT,
                    const float* __restrict__ bias, bf16* __restrict__ C,
                    int M, int N, int K, int ld)
{
    __shared__ bf16 As_[2][2][8192];   // [dbuf][half][128 rows x 64 k]
    __shared__ bf16 Bs_[2][2][8192];
    const int nb = N >> 8;
    const int chunk = (int)gridDim.x >> 3;
    const int idx = ((int)blockIdx.x & 7) * chunk + ((int)blockIdx.x >> 3);
    const int bm = idx / nb, bn = idx - bm * nb;
    const int tm = bm << 8, tn = bn << 8;
    const int tid = threadIdx.x;
    const int lane = tid & 63, w = tid >> 6;   // 8 waves
    const int wr = w >> 2, wc = w & 3;
    const int lq = lane & 15, hk = lane >> 4;

    const int sr  = lane >> 3;
    const int sgo = (((lane & 7) ^ sr) << 3);
    const bf16* gA0 = A  + (size_t)(tm +       w * 8 + sr) * ld + sgo;
    const bf16* gA1 = A  + (size_t)(tm + 128 + w * 8 + sr) * ld + sgo;
    const bf16* gB0 = BT + (size_t)(tn +       w * 8 + sr) * ld + sgo;
    const bf16* gB1 = BT + (size_t)(tn + 128 + w * 8 + sr) * ld + sgo;
    const size_t l64 = (size_t)64 * ld;

#define STG_A0(D, T) do { const size_t ko_ = (size_t)(T) * 64;              \
        GLDS16(gA0 + ko_,       &As_[D][0][w * 512]);                       \
        GLDS16(gA0 + ko_ + l64, &As_[D][0][4096 + w * 512]); } while (0)
#define STG_A1(D, T) do { const size_t ko_ = (size_t)(T) * 64;              \
        GLDS16(gA1 + ko_,       &As_[D][1][w * 512]);                       \
        GLDS16(gA1 + ko_ + l64, &As_[D][1][4096 + w * 512]); } while (0)
#define STG_B0(D, T) do { const size_t ko_ = (size_t)(T) * 64;              \
        GLDS16(gB0 + ko_,       &Bs_[D][0][w * 512]);                       \
        GLDS16(gB0 + ko_ + l64, &Bs_[D][0][4096 + w * 512]); } while (0)
#define STG_B1(D, T) do { const size_t ko_ = (size_t)(T) * 64;              \
        GLDS16(gB1 + ko_,       &Bs_[D][1][w * 512]);                       \
        GLDS16(gB1 + ko_ + l64, &Bs_[D][1][4096 + w * 512]); } while (0)

    f32x4 acc[8][4] = {};
    const int NT = K >> 6;

    STG_A0(0, 0); STG_B1(0, 0); STG_B0(0, 0); STG_A1(0, 0);
    STG_B0(1, 1); STG_A1(1, 1);

    for (int t = 0; t < NT; ++t) {
        const int d = t & 1, e = d ^ 1;
        if (t == NT - 1) asm volatile("s_waitcnt vmcnt(0)" ::: "memory");
        else             asm volatile("s_waitcnt vmcnt(4)" ::: "memory");
        __builtin_amdgcn_s_barrier();
        MEMFENCE;

        const char* Ah0 = (const char*)&As_[d][0][0];
        const char* Ah1 = (const char*)&As_[d][1][0];
        const char* Bh0 = (const char*)&Bs_[d][0][0];
        const char* Bh1 = (const char*)&Bs_[d][1][0];
        bf16x8 af[4][2], bfv[2][2];

#define DO_MFMA(MH, NH) do {                                                 \
        __builtin_amdgcn_s_setprio(1);                                       \
        _Pragma("unroll")                                                    \
        for (int mi = 0; mi < 4; ++mi)                                       \
            _Pragma("unroll")                                                \
            for (int nj = 0; nj < 2; ++nj)                                   \
                _Pragma("unroll")                                            \
                for (int kk = 0; kk < 2; ++kk)                               \
                    acc[(MH)*4+mi][(NH)*2+nj] =                              \
                        mfma16(bfv[nj][kk], af[mi][kk], acc[(MH)*4+mi][(NH)*2+nj]); \
        __builtin_amdgcn_s_setprio(0); } while (0)

        {   // ph1 (0,0)
            #pragma unroll
            for (int mi = 0; mi < 4; ++mi) {
                const int lr = wr * 64 + mi * 16 + lq;
                af[mi][0] = *(const bf16x8*)(Ah0 + lr * 128 + ((hk ^ (lr & 7)) << 4));
                af[mi][1] = *(const bf16x8*)(Ah0 + lr * 128 + (((4 + hk) ^ (lr & 7)) << 4));
            }
            #pragma unroll
            for (int nj = 0; nj < 2; ++nj) {
                const int lc = wc * 32 + nj * 16 + lq;
                bfv[nj][0] = *(const bf16x8*)(Bh0 + lc * 128 + ((hk ^ (lc & 7)) << 4));
                bfv[nj][1] = *(const bf16x8*)(Bh0 + lc * 128 + (((4 + hk) ^ (lc & 7)) << 4));
            }
            if (t + 1 < NT) STG_A0(e, t + 1);
            DO_MFMA(0, 0);
        }
        MEMFENCE; __builtin_amdgcn_s_barrier(); MEMFENCE;
        {   // ph2 (1,0)
            #pragma unroll
            for (int mi = 0; mi < 4; ++mi) {
                const int lr = wr * 64 + mi * 16 + lq;
                af[mi][0] = *(const bf16x8*)(Ah1 + lr * 128 + ((hk ^ (lr & 7)) << 4));
                af[mi][1] = *(const bf16x8*)(Ah1 + lr * 128 + (((4 + hk) ^ (lr & 7)) << 4));
            }
            if (t + 1 < NT) STG_B1(e, t + 1);
            DO_MFMA(1, 0);
        }
        MEMFENCE; __builtin_amdgcn_s_barrier(); MEMFENCE;
        {   // ph3 (1,1)
            #pragma unroll
            for (int nj = 0; nj < 2; ++nj) {
                const int lc = wc * 32 + nj * 16 + lq;
                bfv[nj][0] = *(const bf16x8*)(Bh1 + lc * 128 + ((hk ^ (lc & 7)) << 4));
                bfv[nj][1] = *(const bf16x8*)(Bh1 + lc * 128 + (((4 + hk) ^ (lc & 7)) << 4));
            }
            if (t + 2 < NT) STG_B0(d, t + 2);
            DO_MFMA(1, 1);
        }
        MEMFENCE; __builtin_amdgcn_s_barrier(); MEMFENCE;
        {   // ph4 (0,1)
            #pragma unroll
            for (int mi = 0; mi < 4; ++mi) {
                const int lr = wr * 64 + mi * 16 + lq;
                af[mi][0] = *(const bf16x8*)(Ah0 + lr * 128 + ((hk ^ (lr & 7)) << 4));
                af[mi][1] = *(const bf16x8*)(Ah0 + lr * 128 + (((4 + hk) ^ (lr & 7)) << 4));
            }
            if (t + 2 < NT) STG_A1(d, t + 2);
            DO_MFMA(0, 1);
        }
        MEMFENCE; __builtin_amdgcn_s_barrier(); MEMFENCE;
#undef DO_MFMA
    }
#undef STG_A0
#undef STG_A1
#undef STG_B0
#undef STG_B1

    #pragma unroll
    for (int i = 0; i < 8; ++i) {
        const int mh = i >> 2, mi = i & 3;
        const int row = tm + mh * 128 + wr * 64 + mi * 16 + lq;
        #pragma unroll
        for (int j = 0; j < 4; ++j) {
            const int nh = j >> 1, nj = j & 1;
            const int col = tn + nh * 128 + wc * 32 + nj * 16 + (hk << 2);
            if (EPI == 0) {
                bf16x4 pk = { (bf16)acc[i][j][0], (bf16)acc[i][j][1],
                              (bf16)acc[i][j][2], (bf16)acc[i][j][3] };
                *(bf16x4*)(C + (size_t)row * N + col) = pk;
            } else {
                const float4 bv4 = *(const float4*)(bias + col);
                float v0 = acc[i][j][0] + bv4.x, v1 = acc[i][j][1] + bv4.y;
                float v2 = acc[i][j][2] + bv4.z, v3 = acc[i][j][3] + bv4.w;
                bf16x4 pk = {
                    (bf16)(0.5f * v0 * (1.0f + erff(v0 * 0.70710678118654752f))),
                    (bf16)(0.5f * v1 * (1.0f + erff(v1 * 0.70710678118654752f))),
                    (bf16)(0.5f * v2 * (1.0f + erff(v2 * 0.70710678118654752f))),
                    (bf16)(0.5f * v3 * (1.0f + erff(v3 * 0.70710678118654752f))) };
                *(bf16x4*)(C + (size_t)row * N + col) = pk;
            }
        }
    }
}

// ---------------------------------------------------------------------------
// 128x128 3-stage counted-vmcnt GEMM + swapped-operand vectorized epilogue.
// Used for QKV (768 blk, 3/CU), out-proj, FF2 split-K.
// EPI: 0 = bf16 out; 1 = +bias +fp32res, fp32 out (fallback);
//      3 = split-K partial (BF16); 4 = +bias +fp32res, BF16 out (x2 bf16)
// ---------------------------------------------------------------------------
template<int EPI>
__global__ __launch_bounds__(256, 3)
void gemm_bt_kernel(const bf16* __restrict__ A, const bf16* __restrict__ BT,
                    const float* __restrict__ bias, const float* __restrict__ res,
                    void* __restrict__ Cout, int M, int N, int K, int ld)
{
    __shared__ bf16 As[3][4096];   // [buf][128 m][32 k]
    __shared__ bf16 Bs[3][4096];
    const int nb = N >> 7;
    const int chunk = (int)gridDim.x >> 3;
    int idx = (blockIdx.x & 7) * chunk + (blockIdx.x >> 3);
    int ks = 0;
    if (EPI == 3) {
        const int tiles = (M >> 7) * nb;
        ks = idx / tiles;
        idx -= ks * tiles;
    }
    const int bm = idx / nb, bn = idx - bm * nb;
    const int tm = bm << 7, tn = bn << 7;
    const int tid = threadIdx.x;
    const int lane = tid & 63, wave = tid >> 6;
    const int wm = (wave >> 1) << 6, wn = (wave & 1) << 6;
    const int kofs = ks * K;

    const bf16* ga = A  + (size_t)(tm + wave * 32 + (lane >> 2)) * ld + kofs + ((lane & 3) << 3);
    const bf16* gb = BT + (size_t)(tn + wave * 32 + (lane >> 2)) * ld + kofs + ((lane & 3) << 3);
    const size_t k16 = (size_t)16 * ld;

    f32x4 acc[4][4] = {};
    const int ro = (lane & 15) * 32 + ((lane >> 4) << 3);

#define GSTAGE(BUF, KO) do {                          \
        bf16* la_ = &As[BUF][wave * 1024];            \
        bf16* lb_ = &Bs[BUF][wave * 1024];            \
        GLDS16(ga + (KO),       la_);                 \
        GLDS16(ga + (KO) + k16, la_ + 512);           \
        GLDS16(gb + (KO),       lb_);                 \
        GLDS16(gb + (KO) + k16, lb_ + 512);           \
    } while (0)

    GSTAGE(0, 0);
    GSTAGE(1, 32);
    GSTAGE(2, 64);
    int cur = 0;
    for (int k0 = 0; k0 < K; k0 += 32) {
        if (k0 + 96 <= K)      asm volatile("s_waitcnt vmcnt(8)" ::: "memory");
        else if (k0 + 64 <= K) asm volatile("s_waitcnt vmcnt(4)" ::: "memory");
        else                   asm volatile("s_waitcnt vmcnt(0)" ::: "memory");
        __builtin_amdgcn_s_barrier();

        bf16x8 af[4], bfr[4];
        #pragma unroll
        for (int i = 0; i < 4; ++i) {
            af[i]  = *(const bf16x8*)(&As[cur][0] + (wm + i * 16) * 32 + ro);
            bfr[i] = *(const bf16x8*)(&Bs[cur][0] + (wn + i * 16) * 32 + ro);
        }
        #pragma unroll
        for (int i = 0; i < 4; ++i)
            #pragma unroll
            for (int j = 0; j < 4; ++j)
                acc[i][j] = mfma16(bfr[j], af[i], acc[i][j]);   // swapped

        MEMFENCE;
        __builtin_amdgcn_s_barrier();
        MEMFENCE;
        if (k0 + 96 < K) GSTAGE(cur, k0 + 96);
        cur = (cur == 2) ? 0 : cur + 1;
    }
#undef GSTAGE

    // swapped layout: acc[i][j][r] = C[tm+wm+i*16+lq][tn+wn+j*16+hk*4+r]
    const int lq = lane & 15, hk = lane >> 4;
    const int r0 = tm + wm + lq;
    const int c0 = tn + wn + (hk << 2);
    if (EPI == 0) {
        bf16* C = (bf16*)Cout;
        #pragma unroll
        for (int j = 0; j < 4; ++j)
            #pragma unroll
            for (int i = 0; i < 4; ++i) {
                bf16x4 pk = { (bf16)acc[i][j][0], (bf16)acc[i][j][1],
                              (bf16)acc[i][j][2], (bf16)acc[i][j][3] };
                *(bf16x4*)(C + (size_t)(r0 + i * 16) * N + c0 + j * 16) = pk;
            }
    } else if (EPI == 1) {
        float* C = (float*)Cout;
        #pragma unroll
        for (int j = 0; j < 4; ++j) {
            const float4 bv4 = *(const float4*)(bias + c0 + j * 16);
            #pragma unroll
            for (int i = 0; i < 4; ++i) {
                const size_t off = (size_t)(r0 + i * 16) * N + c0 + j * 16;
                const float4 rv = *(const float4*)(res + off);
                float4 o;
                o.x = acc[i][j][0] + bv4.x + rv.x;
                o.y = acc[i][j][1] + bv4.y + rv.y;
                o.z = acc[i][j][2] + bv4.z + rv.z;
                o.w = acc[i][j][3] + bv4.w + rv.w;
                *(float4*)(C + off) = o;
            }
        }
    } else if (EPI == 4) {   // +bias +fp32 residual, BF16 out (x2 in bf16)
        bf16* C = (bf16*)Cout;
        #pragma unroll
        for (int j = 0; j < 4; ++j) {
            const float4 bv4 = *(const float4*)(bias + c0 + j * 16);
            #pragma unroll
            for (int i = 0; i < 4; ++i) {
                const size_t off = (size_t)(r0 + i * 16) * N + c0 + j * 16;
                const float4 rv = *(const float4*)(res + off);
                bf16x4 pk = { (bf16)(acc[i][j][0] + bv4.x + rv.x),
                              (bf16)(acc[i][j][1] + bv4.y + rv.y),
                              (bf16)(acc[i][j][2] + bv4.z + rv.z),
                              (bf16)(acc[i][j][3] + bv4.w + rv.w) };
                *(bf16x4*)(C + off) = pk;
            }
        }
    } else {   // EPI == 3: BF16 partial, slice ks
        bf16* C = (bf16*)(ks == 0 ? Cout : (void*)res);
        #pragma unroll
        for (int j = 0; j < 4; ++j)
            #pragma unroll
            for (int i = 0; i < 4; ++i) {
                bf16x4 pk = { (bf16)acc[i][j][0], (bf16)acc[i][j][1],
                              (bf16)acc[i][j][2], (bf16)acc[i][j][3] };
                *(bf16x4*)(C + (size_t)(r0 + i * 16) * N + c0 + j * 16) = pk;
            }
    }
}

// ---------------------------------------------------------------------------
// FF2 split-K reduce: out = p0 + p1 + bias + res  (p0/p1/res BF16, out fp32)
// ---------------------------------------------------------------------------
__global__ __launch_bounds__(256) void ff2_reduce_kernel(
    const bf16* __restrict__ p0, const bf16* __restrict__ p1,
    const float* __restrict__ bias, const bf16* __restrict__ res,
    float* __restrict__ out)
{
    const int i = blockIdx.x * 256 + threadIdx.x;    // 4-element index
    const bf16x4 a = ((const bf16x4*)p0)[i];
    const bf16x4 b = ((const bf16x4*)p1)[i];
    const bf16x4 r = ((const bf16x4*)res)[i];
    const float4 g = ((const float4*)bias)[i & 255];
    float4 o;
    o.x = (float)a[0] + (float)b[0] + (float)r[0] + g.x;
    o.y = (float)a[1] + (float)b[1] + (float)r[1] + g.y;
    o.z = (float)a[2] + (float)b[2] + (float)r[2] + g.z;
    o.w = (float)a[3] + (float)b[3] + (float)r[3] + g.w;
    ((float4*)out)[i] = o;
}

// ---------------------------------------------------------------------------
// V transpose per head, PERMUTED columns (r18 proven): within each 32-column
// block, position n' holds V column n with
//   n' = (n&3) | ((n>>4)&1)<<2 | ((n>>2)&3)<<3
// ---------------------------------------------------------------------------
__global__ __launch_bounds__(256) void vtrans_kernel(
    const bf16* __restrict__ qkv, bf16* __restrict__ vT)
{
    __shared__ bf16 t[64 * 64];
    const int n0 = blockIdx.x * 64;
    const int bh = blockIdx.y;
    const int b = bh >> 4, h = bh & 15;
    const bf16* src = qkv + (size_t)(b * SEQ + n0) * QKV3 + 2 * DIMM + h * DHEAD;

    #pragma unroll
    for (int it = 0; it < 2; ++it) {
        const int c = it * 256 + threadIdx.x;
        const int n = c >> 3, d8 = (c & 7) * 8;
        const bf16x8 v8 = *(const bf16x8*)(src + (size_t)n * QKV3 + d8);
        const int byte = (n * 128 + d8 * 2) ^ (((n >> 3) & 7) << 4);
        *(bf16x8*)((char*)t + byte) = v8;
    }
    __syncthreads();
    #pragma unroll
    for (int it = 0; it < 2; ++it) {
        const int c = it * 256 + threadIdx.x;
        const int d = c >> 3, nc = c & 7;
        bf16x8 o8;
        #pragma unroll
        for (int i = 0; i < 8; ++i) {
            const int n = nc * 8 + i;
            const int byte = (n * 128 + d * 2) ^ ((nc & 7) << 4);
            o8[i] = *(const bf16*)((const char*)t + byte);
        }
        bf16* dstrow = vT + (size_t)bh * DHEAD * SEQ + (size_t)d * SEQ;
        #pragma unroll
        for (int half = 0; half < 2; ++half) {
            const int nb2 = nc * 8 + half * 4;
            const int nabs = n0 + nb2;
            const int off = nb2 & 31;
            const int offp = (((off >> 4) & 1) << 2) | (((off >> 2) & 3) << 3);
            bf16x4 q4 = { o8[half * 4 + 0], o8[half * 4 + 1],
                          o8[half * 4 + 2], o8[half * 4 + 3] };
            *(bf16x4*)(dstrow + (nabs & ~31) + offp) = q4;
        }
    }
}

// ---------------------------------------------------------------------------
// Flash attention v8 (r19/r21-proven, 61 us best): P-in-register PV with
// permuted vT', 2x unrolled K-loop (compile-time buffer indices), lane-local
// l with epilogue reduction.
// ---------------------------------------------------------------------------
struct AttnState { float m, l; f32x4 o[4]; };

static __device__ __forceinline__ void attn_body(
    const bf16* __restrict__ Kbuf, const bf16* __restrict__ Vbuf,
    const bf16x8* __restrict__ qf, int q, int hi, AttnState& st)
{
    // S^T = K Q^T : sv[kf][r] = S[kv=kf*16+hi*4+r][q]
    f32x4 sv[4];
    __builtin_amdgcn_s_setprio(1);
    #pragma unroll
    for (int kf = 0; kf < 4; ++kf) {
        f32x4 z = {0.f, 0.f, 0.f, 0.f};
        sv[kf] = z;
        #pragma unroll
        for (int ks = 0; ks < 2; ++ks) {
            const int row = kf * 16 + q;
            const int bo = (row * 128 + ks * 64 + (hi << 4)) ^ ((row & 7) << 4);
            const bf16x8 kfrag = *(const bf16x8*)((const char*)Kbuf + bo);
            sv[kf] = mfma16(kfrag, qf[ks], sv[kf]);
        }
    }
    __builtin_amdgcn_s_setprio(0);

    float pmax;
    {
        float a = fmaxf(fmaxf(sv[0][0], sv[0][1]), fmaxf(sv[0][2], sv[0][3]));
        float b2 = fmaxf(fmaxf(sv[1][0], sv[1][1]), fmaxf(sv[1][2], sv[1][3]));
        float c = fmaxf(fmaxf(sv[2][0], sv[2][1]), fmaxf(sv[2][2], sv[2][3]));
        float d = fmaxf(fmaxf(sv[3][0], sv[3][1]), fmaxf(sv[3][2], sv[3][3]));
        pmax = fmaxf(fmaxf(a, b2), fmaxf(c, d));
    }
    pmax = fmaxf(pmax, __shfl_xor(pmax, 16, 64));
    pmax = fmaxf(pmax, __shfl_xor(pmax, 32, 64));

    if (__any(pmax - st.m > 8.0f)) {
        const float nm = fmaxf(st.m, pmax);
        const float fr = __expf(st.m - nm);
        st.l *= fr;
        #pragma unroll
        for (int df = 0; df < 4; ++df) {
            st.o[df][0] *= fr; st.o[df][1] *= fr;
            st.o[df][2] *= fr; st.o[df][3] *= fr;
        }
        st.m = nm;
    }

    // P = exp(S - m), lane-local l accumulation (reduced in epilogue)
    float pv[4][4];
    float rsum = 0.0f;
    #pragma unroll
    for (int kf = 0; kf < 4; ++kf)
        #pragma unroll
        for (int r = 0; r < 4; ++r) {
            pv[kf][r] = __expf(sv[kf][r] - st.m);
            rsum += pv[kf][r];
        }
    st.l += rsum;

    // pack P into PV B-operands (permuted-k)
    bf16x8 pb[2];
    #pragma unroll
    for (int ks = 0; ks < 2; ++ks)
        #pragma unroll
        for (int r = 0; r < 4; ++r) {
            pb[ks][r]     = (bf16)pv[2 * ks][r];
            pb[ks][r + 4] = (bf16)pv[2 * ks + 1][r];
        }

    // O^T += V^T P^T : conflict-free b128 A-read (permutation baked in vT')
    __builtin_amdgcn_s_setprio(1);
    #pragma unroll
    for (int df = 0; df < 4; ++df) {
        const int rowv = df * 16 + q;
        #pragma unroll
        for (int ks = 0; ks < 2; ++ks) {
            const int bo = (rowv * 128 + ks * 64 + (hi << 4)) ^ ((rowv & 7) << 4);
            const bf16x8 vfrag = *(const bf16x8*)((const char*)Vbuf + bo);
            st.o[df] = mfma16(vfrag, pb[ks], st.o[df]);
        }
    }
    __builtin_amdgcn_s_setprio(0);
}

__global__ __launch_bounds__(256, 4)
void attn_kernel(const bf16* __restrict__ qkv, const bf16* __restrict__ vT,
                 bf16* __restrict__ out)
{
    __shared__ bf16 Ks[2][64 * 64];
    __shared__ bf16 Vs[2][64 * 64];
    const int bid = blockIdx.x;
    const int idx = (bid & 7) * 128 + (bid >> 3);
    const int qt = idx & 31;
    const int bh = idx >> 5;
    const int b = bh >> 4, h = bh & 15;
    const int tid = threadIdx.x;
    const int lane = tid & 63, wave = tid >> 6;
    const int q = lane & 15, hi = lane >> 4;

    const bf16* qbase = qkv + (size_t)(b * SEQ) * QKV3 + h * DHEAD;
    const bf16* kbase = qbase + DIMM;
    const bf16* vbase = vT + (size_t)bh * DHEAD * SEQ;

    const int q0 = qt * 64 + wave * 16;
    bf16x8 qf[2];
    {
        const bf16* qp = qbase + (size_t)(q0 + q) * QKV3 + (hi << 3);
        qf[0] = *(const bf16x8*)qp;
        qf[1] = *(const bf16x8*)(qp + 32);
        #pragma unroll
        for (int j = 0; j < 8; ++j) {
            qf[0][j] = (bf16)((float)qf[0][j] * 0.125f);
            qf[1][j] = (bf16)((float)qf[1][j] * 0.125f);
        }
    }

    const int srow = lane >> 3;
    const int scol = ((lane & 7) ^ srow) << 3;
    const bf16* gk = kbase + (size_t)(wave * 16 + srow) * QKV3 + scol;
    const bf16* gv = vbase + (size_t)(wave * 16 + srow) * SEQ + scol;

#define STAGE(BUF, KT) do {                                        \
        bf16* lk_ = &Ks[BUF][wave * 1024];                         \
        bf16* lv_ = &Vs[BUF][wave * 1024];                         \
        GLDS16(gk + (size_t)(KT) * QKV3,       lk_);               \
        GLDS16(gk + (size_t)((KT) + 8) * QKV3, lk_ + 512);         \
        GLDS16(gv + (KT),                      lv_);               \
        GLDS16(gv + (KT) + 8 * SEQ,            lv_ + 512);         \
    } while (0)

    AttnState st;
    st.m = -1e30f; st.l = 0.0f;
    #pragma unroll
    for (int df = 0; df < 4; ++df) {
        f32x4 z = {0.f, 0.f, 0.f, 0.f};
        st.o[df] = z;
    }

    STAGE(0, 0);
    for (int kt = 0; kt < SEQ; kt += 128) {
        __syncthreads();                       // drains: STAGE(kt) resident
        STAGE(1, kt + 64);                     // always in range (kt+64 <= SEQ-64)
        attn_body(&Ks[0][0], &Vs[0][0], qf, q, hi, st);
        __syncthreads();                       // drains: STAGE(kt+64) resident
        if (kt + 128 < SEQ) STAGE(0, kt + 128);
        attn_body(&Ks[1][0], &Vs[1][0], qf, q, hi, st);
    }
#undef STAGE

    {
        float lt = st.l;
        lt += __shfl_xor(lt, 16, 64);
        lt += __shfl_xor(lt, 32, 64);
        const float inv = 1.0f / lt;
        const int grow = b * SEQ + q0 + q;
        #pragma unroll
        for (int df = 0; df < 4; ++df) {
            bf16x4 pk = { (bf16)(st.o[df][0] * inv), (bf16)(st.o[df][1] * inv),
                          (bf16)(st.o[df][2] * inv), (bf16)(st.o[df][3] * inv) };
            *(bf16x4*)(out + (size_t)grow * DIMM + h * DHEAD + df * 16 + hi * 4) = pk;
        }
    }
}

// ---------------------------------------------------------------------------
extern "C" void kernel_launch(void* const* d_in, const int* in_sizes, int n_in,
                              void* d_out, int out_size, void* d_ws, size_t ws_size,
                              hipStream_t stream)
{
    (void)in_sizes; (void)n_in; (void)out_size;
    const float* x    = (const float*)d_in[0];
    const float* ln1g = (const float*)d_in[1];
    const float* ln1b = (const float*)d_in[2];
    const float* ln2g = (const float*)d_in[3];
    const float* ln2b = (const float*)d_in[4];
    const float* wqkv = (const float*)d_in[5];
    const float* wout = (const float*)d_in[6];
    const float* bout = (const float*)d_in[7];
    const float* wff1 = (const float*)d_in[8];
    const float* bff1 = (const float*)d_in[9];
    const float* wff2 = (const float*)d_in[10];
    const float* bff2 = (const float*)d_in[11];

    char* ws = (char*)d_ws;
    const dim3 blk(256);
    const dim3 blk512(512);
    const bool splitk = ws_size >= 92274688ULL;   // 88 MB packed layout

    if (splitk) {
        bf16*  wff2T = (bf16*)(ws);
        bf16*  woutT = (bf16*)(ws + 8388608);
        bf16*  wff1T = (bf16*)(ws + 10485760);
        bf16*  wqkvT = (bf16*)(ws + 18874368);
        bf16*  hbuf  = (bf16*)(ws + 25165824);
        bf16*  qkvb  = (bf16*)(ws + 33554432);
        bf16*  vT    = (bf16*)(ws + 58720256);
        bf16*  attnb = (bf16*)(ws + 67108864);
        bf16*  x2b   = (bf16*)(ws + 75497472);    // 8 MB bf16 residual stream
        bf16*  fbuf  = (bf16*)(ws + 41943040);
        bf16*  p0    = (bf16*)(ws + 8388608);     // 8 MB bf16 partial (dead woutT/wff1T)
        bf16*  p1    = (bf16*)(ws + 25165824);    // 8 MB bf16 partial (dead hbuf)

        prep_kernel<<<dim3(16384), blk, 0, stream>>>(
            wqkv, wqkvT, wout, woutT, wff1, wff1T, wff2, wff2T,
            x, ln1g, ln1b, hbuf);
        gemm_bt_kernel<0><<<(NROWS / 128) * (QKV3 / 128), blk, 0, stream>>>(
            hbuf, wqkvT, nullptr, nullptr, qkvb, NROWS, QKV3, DIMM, DIMM);
        vtrans_kernel<<<dim3(SEQ / 64, BATCH * NHEAD), blk, 0, stream>>>(qkvb, vT);
        attn_kernel<<<dim3(1024), blk, 0, stream>>>(qkvb, vT, attnb);
        gemm_bt_kernel<4><<<(NROWS / 128) * (DIMM / 128), blk, 0, stream>>>(
            attnb, woutT, bout, x, x2b, NROWS, DIMM, DIMM, DIMM);
        ln_cast_b_kernel<<<NROWS, blk, 0, stream>>>(x2b, ln2g, ln2b, hbuf);
        gemm256_kernel<2><<<(NROWS / 256) * (FFD / 256), blk512, 0, stream>>>(
            hbuf, wff1T, bff1, fbuf, NROWS, FFD, DIMM, DIMM);
        gemm_bt_kernel<3><<<2 * (NROWS / 128) * (DIMM / 128), blk, 0, stream>>>(
            fbuf, wff2T, nullptr, (const float*)p1, p0, NROWS, DIMM, FFD / 2, FFD);
        ff2_reduce_kernel<<<(NROWS * DIMM) / 1024, blk, 0, stream>>>(
            p0, p1, bff2, x2b, (float*)d_out);
    } else {
        // Fallback (ws < 88 MB): fp32 x2 path, single-pass FF2 (r4-proven).
        bf16*  wqkvT = (bf16*)(ws);
        bf16*  woutT = (bf16*)(ws + 6291456);
        bf16*  wff1T = (bf16*)(ws + 8388608);
        bf16*  wff2T = (bf16*)(ws + 16777216);
        float* x2    = (float*)(ws + 25165824);
        bf16*  vT    = (bf16*)(ws + 25165824);
        bf16*  hbuf  = (bf16*)(ws + 41943040);
        bf16*  qkvb  = (bf16*)(ws + 50331648);
        bf16*  attnb = (bf16*)(ws + 75497472);
        bf16*  fbuf  = (bf16*)(ws + 50331648);

        prep_kernel<<<dim3(16384), blk, 0, stream>>>(
            wqkv, wqkvT, wout, woutT, wff1, wff1T, wff2, wff2T,
            x, ln1g, ln1b, hbuf);
        gemm_bt_kernel<0><<<(NROWS / 128) * (QKV3 / 128), blk, 0, stream>>>(
            hbuf, wqkvT, nullptr, nullptr, qkvb, NROWS, QKV3, DIMM, DIMM);
        vtrans_kernel<<<dim3(SEQ / 64, BATCH * NHEAD), blk, 0, stream>>>(qkvb, vT);
        attn_kernel<<<dim3(1024), blk, 0, stream>>>(qkvb, vT, attnb);
        gemm_bt_kernel<1><<<(NROWS / 128) * (DIMM / 128), blk, 0, stream>>>(
            attnb, woutT, bout, x, x2, NROWS, DIMM, DIMM, DIMM);
        ln_cast_kernel<<<NROWS, blk, 0, stream>>>(x2, ln2g, ln2b, hbuf);
        gemm256_kernel<2><<<(NROWS / 256) * (FFD / 256), blk512, 0, stream>>>(
            hbuf, wff1T, bff1, fbuf, NROWS, FFD, DIMM, DIMM);
        gemm_bt_kernel<1><<<(NROWS / 128) * (DIMM / 128), blk, 0, stream>>>(
            fbuf, wff2T, bff2, x2, (float*)d_out, NROWS, DIMM, FFD, FFD);
    }
}